// Round 3
// baseline (814.680 us; speedup 1.0000x reference)
//
#include <hip/hip_runtime.h>

#define IN_DIM 128
#define HID    32

// ---------------- degree / normalization ----------------

__global__ __launch_bounds__(256) void k_init_deg(float* __restrict__ deg, int N) {
    int i = blockIdx.x * 256 + threadIdx.x;
    if (i < N) deg[i] = 1.0f;  // self-loop
}

__global__ __launch_bounds__(256) void k_deg_scatter(const int* __restrict__ col,
                                                     float* __restrict__ deg, int E) {
    int e = blockIdx.x * 256 + threadIdx.x;
    if (e < E) atomicAdd(&deg[col[e]], 1.0f);
}

__global__ __launch_bounds__(256) void k_dinv(float* __restrict__ deg, int N) {
    int i = blockIdx.x * 256 + threadIdx.x;
    if (i < N) deg[i] = rsqrtf(deg[i]);  // deg >= 1 always
}

// ---------------- layer 1 transform: s1 = dinv * (x @ W1) ----------------
// block = 256 threads = 32 nodes x 8 feature-quads. W1 (16KB) staged in LDS.
// Writes s1 into B and also into A (accumulator init == self-loop term).

__global__ __launch_bounds__(256) void k_xform1(const float* __restrict__ x,
                                                const float* __restrict__ W,
                                                const float* __restrict__ dinv,
                                                float* __restrict__ B,
                                                float* __restrict__ A, int N) {
    __shared__ float lw[IN_DIM * HID];  // 16 KB
    for (int i = threadIdx.x; i < IN_DIM * HID; i += 256) lw[i] = W[i];
    __syncthreads();

    int jb = (threadIdx.x & 7) * 4;        // feature quad base: 0,4,...,28
    int nl = threadIdx.x >> 3;             // local node 0..31
    int n  = blockIdx.x * 32 + nl;
    if (n >= N) return;

    const float* xr = x + (size_t)n * IN_DIM;
    float a0 = 0.f, a1 = 0.f, a2 = 0.f, a3 = 0.f;
    #pragma unroll 8
    for (int k = 0; k < IN_DIM; ++k) {
        float xv = xr[k];                  // broadcast within 8-lane group
        const float* wp = &lw[k * HID + jb];
        a0 = fmaf(xv, wp[0], a0);
        a1 = fmaf(xv, wp[1], a1);
        a2 = fmaf(xv, wp[2], a2);
        a3 = fmaf(xv, wp[3], a3);
    }
    float dv = dinv[n];
    float4 v = make_float4(a0 * dv, a1 * dv, a2 * dv, a3 * dv);
    size_t o = (size_t)n * HID + jb;
    *(float4*)(B + o) = v;                 // fully coalesced across the wave
    *(float4*)(A + o) = v;
}

// ---------------- layer 2 transform: s2 = dinv * (h1 @ W2) ----------------

__global__ __launch_bounds__(256) void k_xform2(const float* __restrict__ H,
                                                const float* __restrict__ W,
                                                const float* __restrict__ dinv,
                                                float* __restrict__ B, int N) {
    __shared__ float lw[HID * HID];        // 4 KB
    for (int i = threadIdx.x; i < HID * HID; i += 256) lw[i] = W[i];
    __syncthreads();

    int jb = (threadIdx.x & 7) * 4;
    int nl = threadIdx.x >> 3;
    int n  = blockIdx.x * 32 + nl;
    if (n >= N) return;

    const float* hr = H + (size_t)n * HID;
    float a0 = 0.f, a1 = 0.f, a2 = 0.f, a3 = 0.f;
    #pragma unroll
    for (int k = 0; k < HID; ++k) {
        float hv = hr[k];
        const float* wp = &lw[k * HID + jb];
        a0 = fmaf(hv, wp[0], a0);
        a1 = fmaf(hv, wp[1], a1);
        a2 = fmaf(hv, wp[2], a2);
        a3 = fmaf(hv, wp[3], a3);
    }
    float dv = dinv[n];
    float4 v = make_float4(a0 * dv, a1 * dv, a2 * dv, a3 * dv);
    *(float4*)(B + (size_t)n * HID + jb) = v;
}

// ---------------- edge scatter, width-32 features ----------------
// one lane per (edge, feature); 32-lane group shares an edge.

__global__ __launch_bounds__(256) void k_scatter32(const int* __restrict__ row,
                                                   const int* __restrict__ col,
                                                   const float* __restrict__ B,
                                                   float* __restrict__ A, int E) {
    int idx = blockIdx.x * 256 + threadIdx.x;
    int e = idx >> 5;
    int j = idx & 31;
    if (e < E) {
        int r = row[e];
        int c = col[e];
        atomicAdd(&A[(size_t)c * HID + j], B[(size_t)r * HID + j]);
    }
}

// ---------------- finalize: h = relu(dinv * acc + b), in place ----------------

__global__ __launch_bounds__(256) void k_finalize_relu(float* __restrict__ A,
                                                       const float* __restrict__ dinv,
                                                       const float* __restrict__ b, int N) {
    int i4 = blockIdx.x * 256 + threadIdx.x;   // one float4 per thread
    int n  = i4 >> 3;
    int jb = (i4 & 7) * 4;
    if (n >= N) return;
    float dv = dinv[n];
    size_t o = (size_t)n * HID + jb;
    float4 v = *(float4*)(A + o);
    v.x = fmaxf(fmaf(dv, v.x, b[jb + 0]), 0.f);
    v.y = fmaxf(fmaf(dv, v.y, b[jb + 1]), 0.f);
    v.z = fmaxf(fmaf(dv, v.z, b[jb + 2]), 0.f);
    v.w = fmaxf(fmaf(dv, v.w, b[jb + 3]), 0.f);
    *(float4*)(A + o) = v;
}

// ---------------- copy B -> A (accumulator init for layer 2) ----------------

__global__ __launch_bounds__(256) void k_copy4(const float4* __restrict__ src,
                                               float4* __restrict__ dst, int n4) {
    int i = blockIdx.x * 256 + threadIdx.x;
    if (i < n4) dst[i] = src[i];
}

// ---------------- layer 3 transform: s3 = dinv * (h2 @ W3) ----------------
// 8 lanes per node, float4 loads, shuffle-reduce within 8 lanes.

__global__ __launch_bounds__(256) void k_xform3(const float* __restrict__ H,
                                                const float* __restrict__ W3,
                                                const float* __restrict__ dinv,
                                                float* __restrict__ s3,
                                                float* __restrict__ out, int N) {
    __shared__ float lw[HID];
    if (threadIdx.x < HID) lw[threadIdx.x] = W3[threadIdx.x];
    __syncthreads();

    int jb = (threadIdx.x & 7) * 4;
    int nl = threadIdx.x >> 3;
    int n  = blockIdx.x * 32 + nl;
    if (n >= N) return;

    const float4 hv = *(const float4*)(H + (size_t)n * HID + jb);
    float p = hv.x * lw[jb] + hv.y * lw[jb + 1] + hv.z * lw[jb + 2] + hv.w * lw[jb + 3];
    p += __shfl_xor(p, 1, 8);
    p += __shfl_xor(p, 2, 8);
    p += __shfl_xor(p, 4, 8);
    if ((threadIdx.x & 7) == 0) {
        float sv = p * dinv[n];
        s3[n]  = sv;   // message value
        out[n] = sv;   // accumulator init = self-loop term
    }
}

// ---------------- scalar edge scatter for layer 3 ----------------

__global__ __launch_bounds__(256) void k_scatter1(const int* __restrict__ row,
                                                  const int* __restrict__ col,
                                                  const float* __restrict__ s3,
                                                  float* __restrict__ out, int E) {
    int e = blockIdx.x * 256 + threadIdx.x;
    if (e < E) atomicAdd(&out[col[e]], s3[row[e]]);
}

__global__ __launch_bounds__(256) void k_finout(float* __restrict__ out,
                                                const float* __restrict__ dinv,
                                                const float* __restrict__ b3, int N) {
    int n = blockIdx.x * 256 + threadIdx.x;
    if (n < N) out[n] = fmaf(dinv[n], out[n], b3[0]);
}

// ---------------- host launch ----------------

extern "C" void kernel_launch(void* const* d_in, const int* in_sizes, int n_in,
                              void* d_out, int out_size, void* d_ws, size_t ws_size,
                              hipStream_t stream) {
    const float* x   = (const float*)d_in[0];
    const int*   ei  = (const int*)d_in[1];   // int64 in source collapses to int32 (jax x64 off)
    const float* W1  = (const float*)d_in[2];
    const float* b1  = (const float*)d_in[3];
    const float* W2  = (const float*)d_in[4];
    const float* b2  = (const float*)d_in[5];
    const float* W3  = (const float*)d_in[6];
    const float* b3  = (const float*)d_in[7];

    const int N = in_sizes[0] / IN_DIM;       // 100000
    const int E = in_sizes[1] / 2;            // 2400000
    const int* row = ei;                       // message source
    const int* col = ei + E;                   // aggregation target

    float* ws   = (float*)d_ws;
    float* dinv = ws;                          // [N]
    float* B    = ws + N;                      // [N*32]  message buffer s
    float* A    = B + (size_t)N * HID;         // [N*32]  accumulator / h
    float* out  = (float*)d_out;               // [N]

    const int gN    = (N + 255) / 256;
    const int gE    = (E + 255) / 256;
    const int gNode = (N + 31) / 32;           // xform kernels: 32 nodes/block
    const int gFin  = ((N * 8) + 255) / 256;   // finalize: 1 float4/thread
    const int gScat = (int)(((long long)E * HID + 255) / 256);
    const int n4    = N * HID / 4;
    const int gCpy  = (n4 + 255) / 256;

    // normalization
    k_init_deg   <<<gN,    256, 0, stream>>>(dinv, N);
    k_deg_scatter<<<gE,    256, 0, stream>>>(col, dinv, E);
    k_dinv       <<<gN,    256, 0, stream>>>(dinv, N);

    // layer 1
    k_xform1       <<<gNode, 256, 0, stream>>>(x, W1, dinv, B, A, N);
    k_scatter32    <<<gScat, 256, 0, stream>>>(row, col, B, A, E);
    k_finalize_relu<<<gFin,  256, 0, stream>>>(A, dinv, b1, N);

    // layer 2
    k_xform2       <<<gNode, 256, 0, stream>>>(A, W2, dinv, B, N);
    k_copy4        <<<gCpy,  256, 0, stream>>>((const float4*)B, (float4*)A, n4);
    k_scatter32    <<<gScat, 256, 0, stream>>>(row, col, B, A, E);
    k_finalize_relu<<<gFin,  256, 0, stream>>>(A, dinv, b2, N);

    // layer 3
    k_xform3   <<<gNode, 256, 0, stream>>>(A, W3, dinv, B, out, N);
    k_scatter1 <<<gE,    256, 0, stream>>>(row, col, B, out, E);
    k_finout   <<<gN,    256, 0, stream>>>(out, dinv, b3, N);
}

// Round 4
// 293.285 us; speedup vs baseline: 2.7778x; 2.7778x over previous
//
#include <hip/hip_runtime.h>

#define IN_DIM 128
#define HID    32

// ======================= CSR build =======================

// rank[e] = arrival order of edge e at its target node; deg[c] = in-degree.
__global__ __launch_bounds__(256) void k_count(const int* __restrict__ col,
                                               int* __restrict__ deg,
                                               int* __restrict__ rank, int E) {
    int e = blockIdx.x * 256 + threadIdx.x;
    if (e < E) rank[e] = atomicAdd(&deg[col[e]], 1);
}

// Exclusive scan, level 1: 1024 elems/block (256 thr x 4), write local
// exclusive prefixes into rowptr and the block total into bsum.
__global__ __launch_bounds__(256) void k_scan1(const int* __restrict__ deg,
                                               int* __restrict__ rowptr,
                                               int* __restrict__ bsum, int N) {
    __shared__ int ls[256];
    int t = threadIdx.x;
    int base = blockIdx.x * 1024 + t * 4;
    int v0 = (base + 0 < N) ? deg[base + 0] : 0;
    int v1 = (base + 1 < N) ? deg[base + 1] : 0;
    int v2 = (base + 2 < N) ? deg[base + 2] : 0;
    int v3 = (base + 3 < N) ? deg[base + 3] : 0;
    int s = v0 + v1 + v2 + v3;
    ls[t] = s;
    __syncthreads();
    for (int off = 1; off < 256; off <<= 1) {
        int x = (t >= off) ? ls[t - off] : 0;
        __syncthreads();
        ls[t] += x;
        __syncthreads();
    }
    int excl = ls[t] - s;
    if (t == 255) bsum[blockIdx.x] = ls[255];
    if (base + 0 < N) rowptr[base + 0] = excl;
    if (base + 1 < N) rowptr[base + 1] = excl + v0;
    if (base + 2 < N) rowptr[base + 2] = excl + v0 + v1;
    if (base + 3 < N) rowptr[base + 3] = excl + v0 + v1 + v2;
}

// Level 2: single block scans the (<=256) block sums. (N <= 262144 supported.)
__global__ __launch_bounds__(256) void k_scan2(const int* __restrict__ bsum,
                                               int* __restrict__ boff, int nb) {
    __shared__ int ls[256];
    int t = threadIdx.x;
    int v = (t < nb) ? bsum[t] : 0;
    ls[t] = v;
    __syncthreads();
    for (int off = 1; off < 256; off <<= 1) {
        int x = (t >= off) ? ls[t - off] : 0;
        __syncthreads();
        ls[t] += x;
        __syncthreads();
    }
    if (t < nb) boff[t] = ls[t] - v;
}

// Level 3: add block offsets; also compute dinv = rsqrt(in-degree + 1 self-loop).
__global__ __launch_bounds__(256) void k_scan3(int* __restrict__ rowptr,
                                               const int* __restrict__ boff,
                                               const int* __restrict__ deg,
                                               float* __restrict__ dinv, int N) {
    int i = blockIdx.x * 256 + threadIdx.x;
    if (i < N) {
        rowptr[i] += boff[i >> 10];
        dinv[i] = rsqrtf((float)deg[i] + 1.0f);
    }
}

// csr[rowptr[col[e]] + rank[e]] = row[e]  (no atomics; positions are unique)
__global__ __launch_bounds__(256) void k_fill(const int* __restrict__ row,
                                              const int* __restrict__ col,
                                              const int* __restrict__ rank,
                                              const int* __restrict__ rowptr,
                                              int* __restrict__ csr, int E) {
    int e = blockIdx.x * 256 + threadIdx.x;
    if (e < E) csr[rowptr[col[e]] + rank[e]] = row[e];
}

// ======================= transforms =======================

// s1 = dinv * (x @ W1); 32 nodes/block x 8 lanes, W1 (16KB) in LDS.
__global__ __launch_bounds__(256) void k_xform1(const float* __restrict__ x,
                                                const float* __restrict__ W,
                                                const float* __restrict__ dinv,
                                                float* __restrict__ B, int N) {
    __shared__ float lw[IN_DIM * HID];
    for (int i = threadIdx.x; i < IN_DIM * HID; i += 256) lw[i] = W[i];
    __syncthreads();

    int jb = (threadIdx.x & 7) * 4;
    int n  = blockIdx.x * 32 + (threadIdx.x >> 3);
    if (n >= N) return;

    const float* xr = x + (size_t)n * IN_DIM;
    float a0 = 0.f, a1 = 0.f, a2 = 0.f, a3 = 0.f;
    #pragma unroll 8
    for (int k = 0; k < IN_DIM; ++k) {
        float xv = xr[k];
        const float* wp = &lw[k * HID + jb];
        a0 = fmaf(xv, wp[0], a0);
        a1 = fmaf(xv, wp[1], a1);
        a2 = fmaf(xv, wp[2], a2);
        a3 = fmaf(xv, wp[3], a3);
    }
    float dv = dinv[n];
    *(float4*)(B + (size_t)n * HID + jb) = make_float4(a0 * dv, a1 * dv, a2 * dv, a3 * dv);
}

// s2 = dinv * (H @ W2)
__global__ __launch_bounds__(256) void k_xform2(const float* __restrict__ H,
                                                const float* __restrict__ W,
                                                const float* __restrict__ dinv,
                                                float* __restrict__ B, int N) {
    __shared__ float lw[HID * HID];
    for (int i = threadIdx.x; i < HID * HID; i += 256) lw[i] = W[i];
    __syncthreads();

    int jb = (threadIdx.x & 7) * 4;
    int n  = blockIdx.x * 32 + (threadIdx.x >> 3);
    if (n >= N) return;

    const float* hr = H + (size_t)n * HID;
    float a0 = 0.f, a1 = 0.f, a2 = 0.f, a3 = 0.f;
    #pragma unroll
    for (int k = 0; k < HID; ++k) {
        float hv = hr[k];
        const float* wp = &lw[k * HID + jb];
        a0 = fmaf(hv, wp[0], a0);
        a1 = fmaf(hv, wp[1], a1);
        a2 = fmaf(hv, wp[2], a2);
        a3 = fmaf(hv, wp[3], a3);
    }
    float dv = dinv[n];
    *(float4*)(B + (size_t)n * HID + jb) = make_float4(a0 * dv, a1 * dv, a2 * dv, a3 * dv);
}

// s3[n] = dinv * (H[n] . W3); 8 lanes/node, shuffle-reduce.
__global__ __launch_bounds__(256) void k_xform3(const float* __restrict__ H,
                                                const float* __restrict__ W3,
                                                const float* __restrict__ dinv,
                                                float* __restrict__ s3, int N) {
    __shared__ float lw[HID];
    if (threadIdx.x < HID) lw[threadIdx.x] = W3[threadIdx.x];
    __syncthreads();

    int jb = (threadIdx.x & 7) * 4;
    int n  = blockIdx.x * 32 + (threadIdx.x >> 3);
    if (n >= N) return;

    const float4 hv = *(const float4*)(H + (size_t)n * HID + jb);
    float p = hv.x * lw[jb] + hv.y * lw[jb + 1] + hv.z * lw[jb + 2] + hv.w * lw[jb + 3];
    p += __shfl_xor(p, 1, 8);
    p += __shfl_xor(p, 2, 8);
    p += __shfl_xor(p, 4, 8);
    if ((threadIdx.x & 7) == 0) s3[n] = p * dinv[n];
}

// ======================= aggregation (gather) =======================

// H[n] = act( dinv[n] * (B[n] + sum_{r in nbrs(n)} B[r]) + bias )
// 8 lanes per node, float4 per lane; fused normalize + bias + relu.
__global__ __launch_bounds__(256) void k_gather32(const int* __restrict__ rowptr,
                                                  const int* __restrict__ deg,
                                                  const int* __restrict__ csr,
                                                  const float* __restrict__ Bm,
                                                  const float* __restrict__ dinv,
                                                  const float* __restrict__ bias,
                                                  float* __restrict__ H, int N, int relu) {
    int lane = threadIdx.x & 7;
    int n    = blockIdx.x * 32 + (threadIdx.x >> 3);
    if (n >= N) return;

    const float4* B4 = (const float4*)Bm;
    float4 acc = B4[(size_t)n * 8 + lane];          // self-loop term
    int s = rowptr[n], cnt = deg[n];
    int k = 0;
    for (; k + 1 < cnt; k += 2) {                    // 2-way unroll for MLP
        int r0 = csr[s + k], r1 = csr[s + k + 1];
        float4 u = B4[(size_t)r0 * 8 + lane];
        float4 w = B4[(size_t)r1 * 8 + lane];
        acc.x += u.x + w.x; acc.y += u.y + w.y;
        acc.z += u.z + w.z; acc.w += u.w + w.w;
    }
    if (k < cnt) {
        float4 u = B4[(size_t)csr[s + k] * 8 + lane];
        acc.x += u.x; acc.y += u.y; acc.z += u.z; acc.w += u.w;
    }
    float dv = dinv[n];
    float4 b4 = ((const float4*)bias)[lane];
    float4 o;
    o.x = fmaf(dv, acc.x, b4.x);
    o.y = fmaf(dv, acc.y, b4.y);
    o.z = fmaf(dv, acc.z, b4.z);
    o.w = fmaf(dv, acc.w, b4.w);
    if (relu) {
        o.x = fmaxf(o.x, 0.f); o.y = fmaxf(o.y, 0.f);
        o.z = fmaxf(o.z, 0.f); o.w = fmaxf(o.w, 0.f);
    }
    ((float4*)H)[(size_t)n * 8 + lane] = o;
}

// out[n] = dinv[n] * (s3[n] + sum_nbrs s3[r]) + b3 ; 8 lanes/node strided.
__global__ __launch_bounds__(256) void k_gather1(const int* __restrict__ rowptr,
                                                 const int* __restrict__ deg,
                                                 const int* __restrict__ csr,
                                                 const float* __restrict__ s3,
                                                 const float* __restrict__ dinv,
                                                 const float* __restrict__ b3,
                                                 float* __restrict__ out, int N) {
    int lane = threadIdx.x & 7;
    int n    = blockIdx.x * 32 + (threadIdx.x >> 3);
    if (n >= N) return;

    int s = rowptr[n], cnt = deg[n];
    float acc = 0.f;
    for (int k = lane; k < cnt; k += 8) acc += s3[csr[s + k]];
    acc += __shfl_xor(acc, 1, 8);
    acc += __shfl_xor(acc, 2, 8);
    acc += __shfl_xor(acc, 4, 8);
    if (lane == 0) out[n] = fmaf(dinv[n], acc + s3[n], b3[0]);
}

// ======================= host launch =======================

static inline size_t align64(size_t x) { return (x + 63) & ~(size_t)63; }

extern "C" void kernel_launch(void* const* d_in, const int* in_sizes, int n_in,
                              void* d_out, int out_size, void* d_ws, size_t ws_size,
                              hipStream_t stream) {
    const float* x   = (const float*)d_in[0];
    const int*   ei  = (const int*)d_in[1];   // jax x64 disabled -> int32
    const float* W1  = (const float*)d_in[2];
    const float* b1  = (const float*)d_in[3];
    const float* W2  = (const float*)d_in[4];
    const float* b2  = (const float*)d_in[5];
    const float* W3  = (const float*)d_in[6];
    const float* b3  = (const float*)d_in[7];

    const int N = in_sizes[0] / IN_DIM;       // 100000
    const int E = in_sizes[1] / 2;            // 2400000
    const int* row = ei;                       // message source
    const int* col = ei + E;                   // aggregation target

    // workspace layout (64B-aligned regions)
    char* p = (char*)d_ws;
    size_t off = 0;
    float* dinv   = (float*)(p + off); off = align64(off + (size_t)N * 4);
    float* B      = (float*)(p + off); off = align64(off + (size_t)N * HID * 4);
    float* H      = (float*)(p + off); off = align64(off + (size_t)N * HID * 4);
    int*   deg    = (int*)  (p + off); off = align64(off + (size_t)N * 4);
    int*   rowptr = (int*)  (p + off); off = align64(off + (size_t)N * 4);
    int*   bsum   = (int*)  (p + off); off = align64(off + 256 * 4);
    int*   boff   = (int*)  (p + off); off = align64(off + 256 * 4);
    int*   rank   = (int*)  (p + off); off = align64(off + (size_t)E * 4);
    int*   csr    = (int*)  (p + off); off = align64(off + (size_t)E * 4);
    float* out    = (float*)d_out;

    const int gN    = (N + 255) / 256;
    const int gE    = (E + 255) / 256;
    const int gNode = (N + 31) / 32;           // 32 nodes/block kernels
    const int nb1   = (N + 1023) / 1024;       // scan level-1 blocks (<=256)

    // ---- CSR build + normalization ----
    hipMemsetAsync(deg, 0, (size_t)N * 4, stream);
    k_count<<<gE,   256, 0, stream>>>(col, deg, rank, E);
    k_scan1<<<nb1,  256, 0, stream>>>(deg, rowptr, bsum, N);
    k_scan2<<<1,    256, 0, stream>>>(bsum, boff, nb1);
    k_scan3<<<gN,   256, 0, stream>>>(rowptr, boff, deg, dinv, N);
    k_fill <<<gE,   256, 0, stream>>>(row, col, rank, rowptr, csr, E);

    // ---- layer 1 ----
    k_xform1  <<<gNode, 256, 0, stream>>>(x, W1, dinv, B, N);
    k_gather32<<<gNode, 256, 0, stream>>>(rowptr, deg, csr, B, dinv, b1, H, N, 1);

    // ---- layer 2 ----
    k_xform2  <<<gNode, 256, 0, stream>>>(H, W2, dinv, B, N);
    k_gather32<<<gNode, 256, 0, stream>>>(rowptr, deg, csr, B, dinv, b2, H, N, 1);

    // ---- layer 3 ----
    k_xform3  <<<gNode, 256, 0, stream>>>(H, W3, dinv, B, N);   // s3 in B
    k_gather1 <<<gNode, 256, 0, stream>>>(rowptr, deg, csr, B, dinv, b3, out, N);
}

// Round 5
// 291.818 us; speedup vs baseline: 2.7917x; 1.0050x over previous
//
#include <hip/hip_runtime.h>

#define IN_DIM 128
#define HID    32

// ======================= CSR build =======================

// 4 edges/thread: int4 col load, 4 independent returning atomics (ILP=4),
// int4 rank store. rank[e] = arrival order at target; deg[c] = in-degree.
__global__ __launch_bounds__(256) void k_count(const int* __restrict__ col,
                                               int* __restrict__ deg,
                                               int* __restrict__ rank, int E) {
    int base = (blockIdx.x * 256 + threadIdx.x) * 4;
    if (base + 3 < E) {
        int4 c = *(const int4*)(col + base);
        int r0 = atomicAdd(&deg[c.x], 1);
        int r1 = atomicAdd(&deg[c.y], 1);
        int r2 = atomicAdd(&deg[c.z], 1);
        int r3 = atomicAdd(&deg[c.w], 1);
        *(int4*)(rank + base) = make_int4(r0, r1, r2, r3);
    } else {
        for (int e = base; e < E; ++e) rank[e] = atomicAdd(&deg[col[e]], 1);
    }
}

// Exclusive scan, level 1: 1024 elems/block (256 thr x int4).
__global__ __launch_bounds__(256) void k_scan1(const int* __restrict__ deg,
                                               int* __restrict__ rowptr,
                                               int* __restrict__ bsum, int N) {
    __shared__ int ls[256];
    int t = threadIdx.x;
    int base = blockIdx.x * 1024 + t * 4;
    int v0 = 0, v1 = 0, v2 = 0, v3 = 0;
    if (base + 3 < N) {
        int4 v = *(const int4*)(deg + base);
        v0 = v.x; v1 = v.y; v2 = v.z; v3 = v.w;
    } else {
        if (base + 0 < N) v0 = deg[base + 0];
        if (base + 1 < N) v1 = deg[base + 1];
        if (base + 2 < N) v2 = deg[base + 2];
        if (base + 3 < N) v3 = deg[base + 3];
    }
    int s = v0 + v1 + v2 + v3;
    ls[t] = s;
    __syncthreads();
    for (int off = 1; off < 256; off <<= 1) {
        int x = (t >= off) ? ls[t - off] : 0;
        __syncthreads();
        ls[t] += x;
        __syncthreads();
    }
    int excl = ls[t] - s;
    if (t == 255) bsum[blockIdx.x] = ls[255];
    if (base + 0 < N) rowptr[base + 0] = excl;
    if (base + 1 < N) rowptr[base + 1] = excl + v0;
    if (base + 2 < N) rowptr[base + 2] = excl + v0 + v1;
    if (base + 3 < N) rowptr[base + 3] = excl + v0 + v1 + v2;
}

// Level 2: single block scans the (<=256) block sums.
__global__ __launch_bounds__(256) void k_scan2(const int* __restrict__ bsum,
                                               int* __restrict__ boff, int nb) {
    __shared__ int ls[256];
    int t = threadIdx.x;
    int v = (t < nb) ? bsum[t] : 0;
    ls[t] = v;
    __syncthreads();
    for (int off = 1; off < 256; off <<= 1) {
        int x = (t >= off) ? ls[t - off] : 0;
        __syncthreads();
        ls[t] += x;
        __syncthreads();
    }
    if (t < nb) boff[t] = ls[t] - v;
}

// Level 3: add block offsets; dinv = rsqrt(in-degree + 1 self-loop).
__global__ __launch_bounds__(256) void k_scan3(int* __restrict__ rowptr,
                                               const int* __restrict__ boff,
                                               const int* __restrict__ deg,
                                               float* __restrict__ dinv, int N) {
    int i = blockIdx.x * 256 + threadIdx.x;
    if (i < N) {
        rowptr[i] += boff[i >> 10];
        dinv[i] = rsqrtf((float)deg[i] + 1.0f);
    }
}

// csr[rowptr[col[e]] + rank[e]] = row[e]; 4 edges/thread for latency overlap.
__global__ __launch_bounds__(256) void k_fill(const int* __restrict__ row,
                                              const int* __restrict__ col,
                                              const int* __restrict__ rank,
                                              const int* __restrict__ rowptr,
                                              int* __restrict__ csr, int E) {
    int base = (blockIdx.x * 256 + threadIdx.x) * 4;
    if (base + 3 < E) {
        int4 c  = *(const int4*)(col + base);
        int4 rk = *(const int4*)(rank + base);
        int4 r  = *(const int4*)(row + base);
        int p0 = rowptr[c.x], p1 = rowptr[c.y], p2 = rowptr[c.z], p3 = rowptr[c.w];
        csr[p0 + rk.x] = r.x;
        csr[p1 + rk.y] = r.y;
        csr[p2 + rk.z] = r.z;
        csr[p3 + rk.w] = r.w;
    } else {
        for (int e = base; e < E; ++e) csr[rowptr[col[e]] + rank[e]] = row[e];
    }
}

// ======================= transforms =======================

// s1 = dinv * (x @ W1); 32 nodes/block x 8 lanes, W1 (16KB) in LDS.
__global__ __launch_bounds__(256) void k_xform1(const float* __restrict__ x,
                                                const float* __restrict__ W,
                                                const float* __restrict__ dinv,
                                                float* __restrict__ B, int N) {
    __shared__ float lw[IN_DIM * HID];
    for (int i = threadIdx.x; i < IN_DIM * HID; i += 256) lw[i] = W[i];
    __syncthreads();

    int jb = (threadIdx.x & 7) * 4;
    int n  = blockIdx.x * 32 + (threadIdx.x >> 3);
    if (n >= N) return;

    const float* xr = x + (size_t)n * IN_DIM;
    float a0 = 0.f, a1 = 0.f, a2 = 0.f, a3 = 0.f;
    #pragma unroll 8
    for (int k = 0; k < IN_DIM; ++k) {
        float xv = xr[k];
        const float* wp = &lw[k * HID + jb];
        a0 = fmaf(xv, wp[0], a0);
        a1 = fmaf(xv, wp[1], a1);
        a2 = fmaf(xv, wp[2], a2);
        a3 = fmaf(xv, wp[3], a3);
    }
    float dv = dinv[n];
    *(float4*)(B + (size_t)n * HID + jb) = make_float4(a0 * dv, a1 * dv, a2 * dv, a3 * dv);
}

// s2 = dinv * (H @ W2)
__global__ __launch_bounds__(256) void k_xform2(const float* __restrict__ H,
                                                const float* __restrict__ W,
                                                const float* __restrict__ dinv,
                                                float* __restrict__ B, int N) {
    __shared__ float lw[HID * HID];
    for (int i = threadIdx.x; i < HID * HID; i += 256) lw[i] = W[i];
    __syncthreads();

    int jb = (threadIdx.x & 7) * 4;
    int n  = blockIdx.x * 32 + (threadIdx.x >> 3);
    if (n >= N) return;

    const float* hr = H + (size_t)n * HID;
    float a0 = 0.f, a1 = 0.f, a2 = 0.f, a3 = 0.f;
    #pragma unroll
    for (int k = 0; k < HID; ++k) {
        float hv = hr[k];
        const float* wp = &lw[k * HID + jb];
        a0 = fmaf(hv, wp[0], a0);
        a1 = fmaf(hv, wp[1], a1);
        a2 = fmaf(hv, wp[2], a2);
        a3 = fmaf(hv, wp[3], a3);
    }
    float dv = dinv[n];
    *(float4*)(B + (size_t)n * HID + jb) = make_float4(a0 * dv, a1 * dv, a2 * dv, a3 * dv);
}

// s3[n] = dinv * (H[n] . W3); 8 lanes/node, shuffle-reduce.
__global__ __launch_bounds__(256) void k_xform3(const float* __restrict__ H,
                                                const float* __restrict__ W3,
                                                const float* __restrict__ dinv,
                                                float* __restrict__ s3, int N) {
    __shared__ float lw[HID];
    if (threadIdx.x < HID) lw[threadIdx.x] = W3[threadIdx.x];
    __syncthreads();

    int jb = (threadIdx.x & 7) * 4;
    int n  = blockIdx.x * 32 + (threadIdx.x >> 3);
    if (n >= N) return;

    const float4 hv = *(const float4*)(H + (size_t)n * HID + jb);
    float p = hv.x * lw[jb] + hv.y * lw[jb + 1] + hv.z * lw[jb + 2] + hv.w * lw[jb + 3];
    p += __shfl_xor(p, 1, 8);
    p += __shfl_xor(p, 2, 8);
    p += __shfl_xor(p, 4, 8);
    if ((threadIdx.x & 7) == 0) s3[n] = p * dinv[n];
}

// ======================= aggregation (gather) =======================

// H[n] = act( dinv[n] * (B[n] + sum_{r in nbrs(n)} B[r]) + bias )
// 8 lanes per node, float4 per lane; 4 neighbor lines in flight.
__global__ __launch_bounds__(256) void k_gather32(const int* __restrict__ rowptr,
                                                  const int* __restrict__ deg,
                                                  const int* __restrict__ csr,
                                                  const float* __restrict__ Bm,
                                                  const float* __restrict__ dinv,
                                                  const float* __restrict__ bias,
                                                  float* __restrict__ H, int N, int relu) {
    int lane = threadIdx.x & 7;
    int n    = blockIdx.x * 32 + (threadIdx.x >> 3);
    if (n >= N) return;

    const float4* B4 = (const float4*)Bm;
    float4 acc = B4[(size_t)n * 8 + lane];          // self-loop term
    int s = rowptr[n], cnt = deg[n];
    int k = 0;
    for (; k + 3 < cnt; k += 4) {
        int r0 = csr[s + k],     r1 = csr[s + k + 1];
        int r2 = csr[s + k + 2], r3 = csr[s + k + 3];
        float4 u0 = B4[(size_t)r0 * 8 + lane];
        float4 u1 = B4[(size_t)r1 * 8 + lane];
        float4 u2 = B4[(size_t)r2 * 8 + lane];
        float4 u3 = B4[(size_t)r3 * 8 + lane];
        acc.x += (u0.x + u1.x) + (u2.x + u3.x);
        acc.y += (u0.y + u1.y) + (u2.y + u3.y);
        acc.z += (u0.z + u1.z) + (u2.z + u3.z);
        acc.w += (u0.w + u1.w) + (u2.w + u3.w);
    }
    for (; k < cnt; ++k) {
        float4 u = B4[(size_t)csr[s + k] * 8 + lane];
        acc.x += u.x; acc.y += u.y; acc.z += u.z; acc.w += u.w;
    }
    float dv = dinv[n];
    float4 b4 = ((const float4*)bias)[lane];
    float4 o;
    o.x = fmaf(dv, acc.x, b4.x);
    o.y = fmaf(dv, acc.y, b4.y);
    o.z = fmaf(dv, acc.z, b4.z);
    o.w = fmaf(dv, acc.w, b4.w);
    if (relu) {
        o.x = fmaxf(o.x, 0.f); o.y = fmaxf(o.y, 0.f);
        o.z = fmaxf(o.z, 0.f); o.w = fmaxf(o.w, 0.f);
    }
    ((float4*)H)[(size_t)n * 8 + lane] = o;
}

// out[n] = dinv[n] * (s3[n] + sum_nbrs s3[r]) + b3 ; 8 lanes/node strided.
__global__ __launch_bounds__(256) void k_gather1(const int* __restrict__ rowptr,
                                                 const int* __restrict__ deg,
                                                 const int* __restrict__ csr,
                                                 const float* __restrict__ s3,
                                                 const float* __restrict__ dinv,
                                                 const float* __restrict__ b3,
                                                 float* __restrict__ out, int N) {
    int lane = threadIdx.x & 7;
    int n    = blockIdx.x * 32 + (threadIdx.x >> 3);
    if (n >= N) return;

    int s = rowptr[n], cnt = deg[n];
    float acc = 0.f;
    for (int k = lane; k < cnt; k += 8) acc += s3[csr[s + k]];
    acc += __shfl_xor(acc, 1, 8);
    acc += __shfl_xor(acc, 2, 8);
    acc += __shfl_xor(acc, 4, 8);
    if (lane == 0) out[n] = fmaf(dinv[n], acc + s3[n], b3[0]);
}

// ======================= host launch =======================

static inline size_t align64(size_t x) { return (x + 63) & ~(size_t)63; }

extern "C" void kernel_launch(void* const* d_in, const int* in_sizes, int n_in,
                              void* d_out, int out_size, void* d_ws, size_t ws_size,
                              hipStream_t stream) {
    const float* x   = (const float*)d_in[0];
    const int*   ei  = (const int*)d_in[1];   // jax x64 disabled -> int32
    const float* W1  = (const float*)d_in[2];
    const float* b1  = (const float*)d_in[3];
    const float* W2  = (const float*)d_in[4];
    const float* b2  = (const float*)d_in[5];
    const float* W3  = (const float*)d_in[6];
    const float* b3  = (const float*)d_in[7];

    const int N = in_sizes[0] / IN_DIM;       // 100000
    const int E = in_sizes[1] / 2;            // 2400000
    const int* row = ei;                       // message source
    const int* col = ei + E;                   // aggregation target

    // workspace layout (64B-aligned regions)
    char* p = (char*)d_ws;
    size_t off = 0;
    float* dinv   = (float*)(p + off); off = align64(off + (size_t)N * 4);
    float* B      = (float*)(p + off); off = align64(off + (size_t)N * HID * 4);
    float* H      = (float*)(p + off); off = align64(off + (size_t)N * HID * 4);
    int*   deg    = (int*)  (p + off); off = align64(off + (size_t)N * 4);
    int*   rowptr = (int*)  (p + off); off = align64(off + (size_t)N * 4);
    int*   bsum   = (int*)  (p + off); off = align64(off + 256 * 4);
    int*   boff   = (int*)  (p + off); off = align64(off + 256 * 4);
    int*   rank   = (int*)  (p + off); off = align64(off + (size_t)E * 4);
    int*   csr    = (int*)  (p + off); off = align64(off + (size_t)E * 4);
    float* out    = (float*)d_out;

    const int gN    = (N + 255) / 256;
    const int gE4   = (E + 1023) / 1024;       // 4 edges/thread
    const int gNode = (N + 31) / 32;           // 32 nodes/block kernels
    const int nb1   = (N + 1023) / 1024;       // scan level-1 blocks (<=256)

    // ---- CSR build + normalization ----
    hipMemsetAsync(deg, 0, (size_t)N * 4, stream);
    k_count<<<gE4,  256, 0, stream>>>(col, deg, rank, E);
    k_scan1<<<nb1,  256, 0, stream>>>(deg, rowptr, bsum, N);
    k_scan2<<<1,    256, 0, stream>>>(bsum, boff, nb1);
    k_scan3<<<gN,   256, 0, stream>>>(rowptr, boff, deg, dinv, N);
    k_fill <<<gE4,  256, 0, stream>>>(row, col, rank, rowptr, csr, E);

    // ---- layer 1 ----
    k_xform1  <<<gNode, 256, 0, stream>>>(x, W1, dinv, B, N);
    k_gather32<<<gNode, 256, 0, stream>>>(rowptr, deg, csr, B, dinv, b1, H, N, 1);

    // ---- layer 2 ----
    k_xform2  <<<gNode, 256, 0, stream>>>(H, W2, dinv, B, N);
    k_gather32<<<gNode, 256, 0, stream>>>(rowptr, deg, csr, B, dinv, b2, H, N, 1);

    // ---- layer 3 ----
    k_xform3  <<<gNode, 256, 0, stream>>>(H, W3, dinv, B, N);   // s3 in B
    k_gather1 <<<gNode, 256, 0, stream>>>(rowptr, deg, csr, B, dinv, b3, out, N);
}

// Round 6
// 234.355 us; speedup vs baseline: 3.4763x; 1.2452x over previous
//
#include <hip/hip_runtime.h>

#define IN_DIM 128
#define HID    32
#define CHUNK  4096      // edges per block in CSR-build kernels
#define BSH    9         // log2(nodes per bucket)
#define BSIZE  512       // nodes per bucket

// ======================= CSR build (bucketed, no scattered global atomics) =======================

// kA: global bucket histogram. LDS-privatized, 196 global atomics per block.
__global__ __launch_bounds__(256) void kA_hist(const int* __restrict__ col,
                                               int* __restrict__ ghist, int E) {
    __shared__ int lh[256];
    int tid = threadIdx.x;
    lh[tid] = 0;
    __syncthreads();
    int base = blockIdx.x * CHUNK;
    int nE = min(CHUNK, E - base);
    for (int i = tid; i < nE; i += 256)
        atomicAdd(&lh[col[base + i] >> BSH], 1);
    __syncthreads();
    if (lh[tid]) atomicAdd(&ghist[tid], lh[tid]);
}

// kA_scan: one block; exclusive scan of 196(<=256) bucket sizes -> gbase, cursor.
__global__ __launch_bounds__(256) void kA_scan(const int* __restrict__ ghist,
                                               int* __restrict__ gbase,
                                               int* __restrict__ cursor) {
    __shared__ int s[256];
    int t = threadIdx.x;
    int v = ghist[t];
    s[t] = v;
    __syncthreads();
    for (int off = 1; off < 256; off <<= 1) {
        int nv = s[t] + (t >= off ? s[t - off] : 0);
        __syncthreads();
        s[t] = nv;
        __syncthreads();
    }
    int excl = s[t] - v;
    gbase[t]  = excl;
    cursor[t] = excl;
    if (t == 255) gbase[256] = s[255];
}

// kB: per-block LDS counting sort by bucket, contiguous reservation, coalesced run writes.
__global__ __launch_bounds__(256) void kB_scatter(const int* __restrict__ row,
                                                  const int* __restrict__ col,
                                                  int* __restrict__ cursor,
                                                  int* __restrict__ bcol,
                                                  int* __restrict__ brow, int E) {
    __shared__ int lh[256];      // per-bucket counts (preserved)
    __shared__ int ls[256];      // exclusive local starts
    __shared__ int gdst[256];    // global_base - local_start per bucket
    __shared__ int c2[256];      // local rank cursors
    __shared__ int sc[CHUNK];    // bucket-sorted cols
    __shared__ int sr[CHUNK];    // bucket-sorted rows
    int tid = threadIdx.x;
    lh[tid] = 0; c2[tid] = 0;
    __syncthreads();

    int base = blockIdx.x * CHUNK;
    int nE = min(CHUNK, E - base);

    // 1) local bucket histogram
    for (int i = tid; i < nE; i += 256)
        atomicAdd(&lh[col[base + i] >> BSH], 1);
    __syncthreads();

    // 2) exclusive scan of local counts
    int v = lh[tid];
    ls[tid] = v;
    __syncthreads();
    for (int off = 1; off < 256; off <<= 1) {
        int nv = ls[tid] + (tid >= off ? ls[tid - off] : 0);
        __syncthreads();
        ls[tid] = nv;
        __syncthreads();
    }
    ls[tid] -= v;                 // exclusive
    __syncthreads();

    // 3) reserve contiguous global space per non-empty bucket
    //    (rotate bucket ownership to decorrelate hot cursor addresses)
    int bb = (tid + blockIdx.x) & 255;
    int vb = lh[bb];
    if (vb) gdst[bb] = atomicAdd(&cursor[bb], vb) - ls[bb];
    __syncthreads();

    // 4) LDS counting-sort scatter
    for (int i = tid; i < nE; i += 256) {
        int c = col[base + i];
        int r = row[base + i];
        int b = c >> BSH;
        int k = atomicAdd(&c2[b], 1);
        int idx = ls[b] + k;
        sc[idx] = c;
        sr[idx] = r;
    }
    __syncthreads();

    // 5) write bucket-sorted runs to global (consecutive lanes -> consecutive dst)
    for (int i = tid; i < nE; i += 256) {
        int c = sc[i];
        int b = c >> BSH;
        int d = gdst[b] + i;
        bcol[d] = c;
        brow[d] = sr[i];
    }
}

// kC: one block per bucket; edges contiguous. Produces deg, rowptr, dinv, csr.
__global__ __launch_bounds__(256) void kC_fill(const int* __restrict__ bcol,
                                               const int* __restrict__ brow,
                                               const int* __restrict__ gbase,
                                               int* __restrict__ csr,
                                               int* __restrict__ rowptr,
                                               int* __restrict__ deg,
                                               float* __restrict__ dinv, int N) {
    __shared__ int cnt[BSIZE], ex[BSIZE], c2[BSIZE];
    int tid = threadIdx.x;
    int b = blockIdx.x;
    int s = gbase[b], e = gbase[b + 1];
    int c0 = b << BSH;

    cnt[tid] = 0; cnt[tid + 256] = 0;
    c2[tid]  = 0; c2[tid + 256]  = 0;
    __syncthreads();

    // 1) local degree histogram
    for (int i = s + tid; i < e; i += 256)
        atomicAdd(&cnt[bcol[i] - c0], 1);
    __syncthreads();

    // 2) inclusive scan of 512 counts (256 threads x 2)
    ex[tid] = cnt[tid]; ex[tid + 256] = cnt[tid + 256];
    __syncthreads();
    for (int off = 1; off < BSIZE; off <<= 1) {
        int j0 = tid, j1 = tid + 256;
        int n0 = ex[j0] + (j0 >= off ? ex[j0 - off] : 0);
        int n1 = ex[j1] + (j1 >= off ? ex[j1 - off] : 0);
        __syncthreads();
        ex[j0] = n0; ex[j1] = n1;
        __syncthreads();
    }

    // 3) to exclusive; emit rowptr / deg / dinv
    for (int j = tid; j < BSIZE; j += 256) {
        int ev = ex[j] - cnt[j];
        ex[j] = ev;                          // own-index rw only
        int n = c0 + j;
        if (n < N) {
            rowptr[n] = s + ev;
            deg[n]    = cnt[j];
            dinv[n]   = rsqrtf((float)cnt[j] + 1.0f);
        }
    }
    __syncthreads();

    // 4) fill csr (writes land within this bucket's ~50KB window)
    for (int i = s + tid; i < e; i += 256) {
        int c = bcol[i] - c0;
        int k = atomicAdd(&c2[c], 1);
        csr[s + ex[c] + k] = brow[i];
    }
}

// ======================= transforms =======================

// s1 = dinv * (x @ W1); 32 nodes/block x 8 lanes, W1 (16KB) in LDS.
__global__ __launch_bounds__(256) void k_xform1(const float* __restrict__ x,
                                                const float* __restrict__ W,
                                                const float* __restrict__ dinv,
                                                float* __restrict__ B, int N) {
    __shared__ float lw[IN_DIM * HID];
    for (int i = threadIdx.x; i < IN_DIM * HID; i += 256) lw[i] = W[i];
    __syncthreads();

    int jb = (threadIdx.x & 7) * 4;
    int n  = blockIdx.x * 32 + (threadIdx.x >> 3);
    if (n >= N) return;

    const float* xr = x + (size_t)n * IN_DIM;
    float a0 = 0.f, a1 = 0.f, a2 = 0.f, a3 = 0.f;
    #pragma unroll 8
    for (int k = 0; k < IN_DIM; ++k) {
        float xv = xr[k];
        const float* wp = &lw[k * HID + jb];
        a0 = fmaf(xv, wp[0], a0);
        a1 = fmaf(xv, wp[1], a1);
        a2 = fmaf(xv, wp[2], a2);
        a3 = fmaf(xv, wp[3], a3);
    }
    float dv = dinv[n];
    *(float4*)(B + (size_t)n * HID + jb) = make_float4(a0 * dv, a1 * dv, a2 * dv, a3 * dv);
}

// s2 = dinv * (H @ W2)
__global__ __launch_bounds__(256) void k_xform2(const float* __restrict__ H,
                                                const float* __restrict__ W,
                                                const float* __restrict__ dinv,
                                                float* __restrict__ B, int N) {
    __shared__ float lw[HID * HID];
    for (int i = threadIdx.x; i < HID * HID; i += 256) lw[i] = W[i];
    __syncthreads();

    int jb = (threadIdx.x & 7) * 4;
    int n  = blockIdx.x * 32 + (threadIdx.x >> 3);
    if (n >= N) return;

    const float* hr = H + (size_t)n * HID;
    float a0 = 0.f, a1 = 0.f, a2 = 0.f, a3 = 0.f;
    #pragma unroll
    for (int k = 0; k < HID; ++k) {
        float hv = hr[k];
        const float* wp = &lw[k * HID + jb];
        a0 = fmaf(hv, wp[0], a0);
        a1 = fmaf(hv, wp[1], a1);
        a2 = fmaf(hv, wp[2], a2);
        a3 = fmaf(hv, wp[3], a3);
    }
    float dv = dinv[n];
    *(float4*)(B + (size_t)n * HID + jb) = make_float4(a0 * dv, a1 * dv, a2 * dv, a3 * dv);
}

// s3[n] = dinv * (H[n] . W3); 8 lanes/node, shuffle-reduce.
__global__ __launch_bounds__(256) void k_xform3(const float* __restrict__ H,
                                                const float* __restrict__ W3,
                                                const float* __restrict__ dinv,
                                                float* __restrict__ s3, int N) {
    __shared__ float lw[HID];
    if (threadIdx.x < HID) lw[threadIdx.x] = W3[threadIdx.x];
    __syncthreads();

    int jb = (threadIdx.x & 7) * 4;
    int n  = blockIdx.x * 32 + (threadIdx.x >> 3);
    if (n >= N) return;

    const float4 hv = *(const float4*)(H + (size_t)n * HID + jb);
    float p = hv.x * lw[jb] + hv.y * lw[jb + 1] + hv.z * lw[jb + 2] + hv.w * lw[jb + 3];
    p += __shfl_xor(p, 1, 8);
    p += __shfl_xor(p, 2, 8);
    p += __shfl_xor(p, 4, 8);
    if ((threadIdx.x & 7) == 0) s3[n] = p * dinv[n];
}

// ======================= aggregation (gather) =======================

__global__ __launch_bounds__(256) void k_gather32(const int* __restrict__ rowptr,
                                                  const int* __restrict__ deg,
                                                  const int* __restrict__ csr,
                                                  const float* __restrict__ Bm,
                                                  const float* __restrict__ dinv,
                                                  const float* __restrict__ bias,
                                                  float* __restrict__ H, int N, int relu) {
    int lane = threadIdx.x & 7;
    int n    = blockIdx.x * 32 + (threadIdx.x >> 3);
    if (n >= N) return;

    const float4* B4 = (const float4*)Bm;
    float4 acc = B4[(size_t)n * 8 + lane];          // self-loop term
    int s = rowptr[n], cnt = deg[n];
    int k = 0;
    for (; k + 3 < cnt; k += 4) {
        int r0 = csr[s + k],     r1 = csr[s + k + 1];
        int r2 = csr[s + k + 2], r3 = csr[s + k + 3];
        float4 u0 = B4[(size_t)r0 * 8 + lane];
        float4 u1 = B4[(size_t)r1 * 8 + lane];
        float4 u2 = B4[(size_t)r2 * 8 + lane];
        float4 u3 = B4[(size_t)r3 * 8 + lane];
        acc.x += (u0.x + u1.x) + (u2.x + u3.x);
        acc.y += (u0.y + u1.y) + (u2.y + u3.y);
        acc.z += (u0.z + u1.z) + (u2.z + u3.z);
        acc.w += (u0.w + u1.w) + (u2.w + u3.w);
    }
    for (; k < cnt; ++k) {
        float4 u = B4[(size_t)csr[s + k] * 8 + lane];
        acc.x += u.x; acc.y += u.y; acc.z += u.z; acc.w += u.w;
    }
    float dv = dinv[n];
    float4 b4 = ((const float4*)bias)[lane];
    float4 o;
    o.x = fmaf(dv, acc.x, b4.x);
    o.y = fmaf(dv, acc.y, b4.y);
    o.z = fmaf(dv, acc.z, b4.z);
    o.w = fmaf(dv, acc.w, b4.w);
    if (relu) {
        o.x = fmaxf(o.x, 0.f); o.y = fmaxf(o.y, 0.f);
        o.z = fmaxf(o.z, 0.f); o.w = fmaxf(o.w, 0.f);
    }
    ((float4*)H)[(size_t)n * 8 + lane] = o;
}

__global__ __launch_bounds__(256) void k_gather1(const int* __restrict__ rowptr,
                                                 const int* __restrict__ deg,
                                                 const int* __restrict__ csr,
                                                 const float* __restrict__ s3,
                                                 const float* __restrict__ dinv,
                                                 const float* __restrict__ b3,
                                                 float* __restrict__ out, int N) {
    int lane = threadIdx.x & 7;
    int n    = blockIdx.x * 32 + (threadIdx.x >> 3);
    if (n >= N) return;

    int s = rowptr[n], cnt = deg[n];
    float acc = 0.f;
    for (int k = lane; k < cnt; k += 8) acc += s3[csr[s + k]];
    acc += __shfl_xor(acc, 1, 8);
    acc += __shfl_xor(acc, 2, 8);
    acc += __shfl_xor(acc, 4, 8);
    if (lane == 0) out[n] = fmaf(dinv[n], acc + s3[n], b3[0]);
}

// ======================= host launch =======================

static inline size_t align64(size_t x) { return (x + 63) & ~(size_t)63; }

extern "C" void kernel_launch(void* const* d_in, const int* in_sizes, int n_in,
                              void* d_out, int out_size, void* d_ws, size_t ws_size,
                              hipStream_t stream) {
    const float* x   = (const float*)d_in[0];
    const int*   ei  = (const int*)d_in[1];   // jax x64 disabled -> int32
    const float* W1  = (const float*)d_in[2];
    const float* b1  = (const float*)d_in[3];
    const float* W2  = (const float*)d_in[4];
    const float* b2  = (const float*)d_in[5];
    const float* W3  = (const float*)d_in[6];
    const float* b3  = (const float*)d_in[7];

    const int N = in_sizes[0] / IN_DIM;       // 100000
    const int E = in_sizes[1] / 2;            // 2400000
    const int* row = ei;                       // message source
    const int* col = ei + E;                   // aggregation target

    // workspace layout (64B-aligned regions)
    char* p = (char*)d_ws;
    size_t off = 0;
    float* dinv   = (float*)(p + off); off = align64(off + (size_t)N * 4);
    float* B      = (float*)(p + off); off = align64(off + (size_t)N * HID * 4);
    float* H      = (float*)(p + off); off = align64(off + (size_t)N * HID * 4);
    int*   deg    = (int*)  (p + off); off = align64(off + (size_t)N * 4);
    int*   rowptr = (int*)  (p + off); off = align64(off + (size_t)N * 4);
    int*   ghist  = (int*)  (p + off); off = align64(off + 256 * 4);
    int*   gbase  = (int*)  (p + off); off = align64(off + 320 * 4);
    int*   cursor = (int*)  (p + off); off = align64(off + 256 * 4);
    int*   csr    = (int*)  (p + off); off = align64(off + (size_t)E * 4);
    float* out    = (float*)d_out;

    // bcol/brow live in the B/H regions (CSR build completes before B/H are used)
    int* bcol = (int*)B;   // E*4 = 9.6MB <= 12.8MB
    int* brow = (int*)H;

    const int gBuild = (E + CHUNK - 1) / CHUNK;   // 586
    const int NB     = (N + BSIZE - 1) / BSIZE;   // 196
    const int gNode  = (N + 31) / 32;             // 32 nodes/block kernels

    // ---- CSR build + normalization ----
    hipMemsetAsync(ghist, 0, 256 * 4, stream);
    kA_hist   <<<gBuild, 256, 0, stream>>>(col, ghist, E);
    kA_scan   <<<1,      256, 0, stream>>>(ghist, gbase, cursor);
    kB_scatter<<<gBuild, 256, 0, stream>>>(row, col, cursor, bcol, brow, E);
    kC_fill   <<<NB,     256, 0, stream>>>(bcol, brow, gbase, csr, rowptr, deg, dinv, N);

    // ---- layer 1 ----
    k_xform1  <<<gNode, 256, 0, stream>>>(x, W1, dinv, B, N);
    k_gather32<<<gNode, 256, 0, stream>>>(rowptr, deg, csr, B, dinv, b1, H, N, 1);

    // ---- layer 2 ----
    k_xform2  <<<gNode, 256, 0, stream>>>(H, W2, dinv, B, N);
    k_gather32<<<gNode, 256, 0, stream>>>(rowptr, deg, csr, B, dinv, b2, H, N, 1);

    // ---- layer 3 ----
    k_xform3  <<<gNode, 256, 0, stream>>>(H, W3, dinv, B, N);   // s3 in B
    k_gather1 <<<gNode, 256, 0, stream>>>(rowptr, deg, csr, B, dinv, b3, out, N);
}

// Round 7
// 193.665 us; speedup vs baseline: 4.2066x; 1.2101x over previous
//
#include <hip/hip_runtime.h>
#include <hip/hip_fp16.h>

#define IN_DIM 128
#define HID    32
#define CHUNK  4096      // edges per block in CSR-build kernels
#define BSH    9         // log2(nodes per bucket)
#define BSIZE  512       // nodes per bucket

typedef union { float2 f2; __half2 h2[2]; } hpack;

// ======================= CSR build (bucketed, no scattered global atomics) =======================

// kA: global bucket histogram. LDS-privatized, ~196 global atomics per block.
__global__ __launch_bounds__(256) void kA_hist(const int* __restrict__ col,
                                               int* __restrict__ ghist, int E) {
    __shared__ int lh[256];
    int tid = threadIdx.x;
    lh[tid] = 0;
    __syncthreads();
    int base = blockIdx.x * CHUNK;
    int nE = min(CHUNK, E - base);
    for (int i = tid; i < nE; i += 256)
        atomicAdd(&lh[col[base + i] >> BSH], 1);
    __syncthreads();
    if (lh[tid]) atomicAdd(&ghist[tid], lh[tid]);
}

// kA_scan: one block; exclusive scan of bucket sizes -> gbase, cursor.
__global__ __launch_bounds__(256) void kA_scan(const int* __restrict__ ghist,
                                               int* __restrict__ gbase,
                                               int* __restrict__ cursor) {
    __shared__ int s[256];
    int t = threadIdx.x;
    int v = ghist[t];
    s[t] = v;
    __syncthreads();
    for (int off = 1; off < 256; off <<= 1) {
        int nv = s[t] + (t >= off ? s[t - off] : 0);
        __syncthreads();
        s[t] = nv;
        __syncthreads();
    }
    int excl = s[t] - v;
    gbase[t]  = excl;
    cursor[t] = excl;
    if (t == 255) gbase[256] = s[255];
}

// kB: per-block LDS counting sort by bucket, contiguous reservation, coalesced run writes.
__global__ __launch_bounds__(256) void kB_scatter(const int* __restrict__ row,
                                                  const int* __restrict__ col,
                                                  int* __restrict__ cursor,
                                                  int* __restrict__ bcol,
                                                  int* __restrict__ brow, int E) {
    __shared__ int lh[256];      // per-bucket counts (preserved)
    __shared__ int ls[256];      // exclusive local starts
    __shared__ int gdst[256];    // global_base - local_start per bucket
    __shared__ int c2[256];      // local rank cursors
    __shared__ int sc[CHUNK];    // bucket-sorted cols
    __shared__ int sr[CHUNK];    // bucket-sorted rows
    int tid = threadIdx.x;
    lh[tid] = 0; c2[tid] = 0;
    __syncthreads();

    int base = blockIdx.x * CHUNK;
    int nE = min(CHUNK, E - base);

    // 1) local bucket histogram
    for (int i = tid; i < nE; i += 256)
        atomicAdd(&lh[col[base + i] >> BSH], 1);
    __syncthreads();

    // 2) exclusive scan of local counts
    int v = lh[tid];
    ls[tid] = v;
    __syncthreads();
    for (int off = 1; off < 256; off <<= 1) {
        int nv = ls[tid] + (tid >= off ? ls[tid - off] : 0);
        __syncthreads();
        ls[tid] = nv;
        __syncthreads();
    }
    ls[tid] -= v;                 // exclusive
    __syncthreads();

    // 3) reserve contiguous global space per non-empty bucket
    int bb = (tid + blockIdx.x) & 255;
    int vb = lh[bb];
    if (vb) gdst[bb] = atomicAdd(&cursor[bb], vb) - ls[bb];
    __syncthreads();

    // 4) LDS counting-sort scatter
    for (int i = tid; i < nE; i += 256) {
        int c = col[base + i];
        int r = row[base + i];
        int b = c >> BSH;
        int k = atomicAdd(&c2[b], 1);
        int idx = ls[b] + k;
        sc[idx] = c;
        sr[idx] = r;
    }
    __syncthreads();

    // 5) write bucket-sorted runs to global (consecutive lanes -> consecutive dst)
    for (int i = tid; i < nE; i += 256) {
        int c = sc[i];
        int b = c >> BSH;
        int d = gdst[b] + i;
        bcol[d] = c;
        brow[d] = sr[i];
    }
}

// kC: one 1024-thread block per bucket (16 waves for latency hiding).
// Produces deg, rowptr, dinv, csr.
__global__ __launch_bounds__(1024) void kC_fill(const int* __restrict__ bcol,
                                                const int* __restrict__ brow,
                                                const int* __restrict__ gbase,
                                                int* __restrict__ csr,
                                                int* __restrict__ rowptr,
                                                int* __restrict__ deg,
                                                float* __restrict__ dinv, int N) {
    __shared__ int cnt[BSIZE], ex[BSIZE], c2[BSIZE];
    int tid = threadIdx.x;
    int b = blockIdx.x;
    int s = gbase[b], e = gbase[b + 1];
    int c0 = b << BSH;

    if (tid < BSIZE) { cnt[tid] = 0; c2[tid] = 0; }
    __syncthreads();

    // 1) local degree histogram
    for (int i = s + tid; i < e; i += 1024)
        atomicAdd(&cnt[bcol[i] - c0], 1);
    __syncthreads();

    // 2) inclusive scan of 512 counts (threads 0..511 active)
    if (tid < BSIZE) ex[tid] = cnt[tid];
    __syncthreads();
    for (int off = 1; off < BSIZE; off <<= 1) {
        int nv = 0;
        if (tid < BSIZE) nv = ex[tid] + (tid >= off ? ex[tid - off] : 0);
        __syncthreads();
        if (tid < BSIZE) ex[tid] = nv;
        __syncthreads();
    }

    // 3) to exclusive; emit rowptr / deg / dinv
    if (tid < BSIZE) {
        int ev = ex[tid] - cnt[tid];
        ex[tid] = ev;
        int n = c0 + tid;
        if (n < N) {
            rowptr[n] = s + ev;
            deg[n]    = cnt[tid];
            dinv[n]   = rsqrtf((float)cnt[tid] + 1.0f);
        }
    }
    __syncthreads();

    // 4) fill csr (writes land within this bucket's ~50KB window)
    for (int i = s + tid; i < e; i += 1024) {
        int c = bcol[i] - c0;
        int k = atomicAdd(&c2[c], 1);
        csr[s + ex[c] + k] = brow[i];
    }
}

// ======================= transforms (messages stored fp16, f32 math) =======================

// s1 = dinv * (x @ W1); 32 nodes/block x 8 lanes, W1 (16KB) in LDS.
__global__ __launch_bounds__(256) void k_xform1(const float* __restrict__ x,
                                                const float* __restrict__ W,
                                                const float* __restrict__ dinv,
                                                float* __restrict__ B, int N) {
    __shared__ float lw[IN_DIM * HID];
    for (int i = threadIdx.x; i < IN_DIM * HID; i += 256) lw[i] = W[i];
    __syncthreads();

    int lane = threadIdx.x & 7;
    int jb = lane * 4;
    int n  = blockIdx.x * 32 + (threadIdx.x >> 3);
    if (n >= N) return;

    const float* xr = x + (size_t)n * IN_DIM;
    float a0 = 0.f, a1 = 0.f, a2 = 0.f, a3 = 0.f;
    #pragma unroll 8
    for (int k = 0; k < IN_DIM; ++k) {
        float xv = xr[k];
        const float* wp = &lw[k * HID + jb];
        a0 = fmaf(xv, wp[0], a0);
        a1 = fmaf(xv, wp[1], a1);
        a2 = fmaf(xv, wp[2], a2);
        a3 = fmaf(xv, wp[3], a3);
    }
    float dv = dinv[n];
    hpack u;
    u.h2[0] = __floats2half2_rn(a0 * dv, a1 * dv);
    u.h2[1] = __floats2half2_rn(a2 * dv, a3 * dv);
    ((float2*)B)[(size_t)n * 8 + lane] = u.f2;
}

// s2 = dinv * (H @ W2)
__global__ __launch_bounds__(256) void k_xform2(const float* __restrict__ H,
                                                const float* __restrict__ W,
                                                const float* __restrict__ dinv,
                                                float* __restrict__ B, int N) {
    __shared__ float lw[HID * HID];
    for (int i = threadIdx.x; i < HID * HID; i += 256) lw[i] = W[i];
    __syncthreads();

    int lane = threadIdx.x & 7;
    int jb = lane * 4;
    int n  = blockIdx.x * 32 + (threadIdx.x >> 3);
    if (n >= N) return;

    const float* hr = H + (size_t)n * HID;
    float a0 = 0.f, a1 = 0.f, a2 = 0.f, a3 = 0.f;
    #pragma unroll
    for (int k = 0; k < HID; ++k) {
        float hv = hr[k];
        const float* wp = &lw[k * HID + jb];
        a0 = fmaf(hv, wp[0], a0);
        a1 = fmaf(hv, wp[1], a1);
        a2 = fmaf(hv, wp[2], a2);
        a3 = fmaf(hv, wp[3], a3);
    }
    float dv = dinv[n];
    hpack u;
    u.h2[0] = __floats2half2_rn(a0 * dv, a1 * dv);
    u.h2[1] = __floats2half2_rn(a2 * dv, a3 * dv);
    ((float2*)B)[(size_t)n * 8 + lane] = u.f2;
}

// s3[n] = dinv * (H[n] . W3); f32, 8 lanes/node, shuffle-reduce.
__global__ __launch_bounds__(256) void k_xform3(const float* __restrict__ H,
                                                const float* __restrict__ W3,
                                                const float* __restrict__ dinv,
                                                float* __restrict__ s3, int N) {
    __shared__ float lw[HID];
    if (threadIdx.x < HID) lw[threadIdx.x] = W3[threadIdx.x];
    __syncthreads();

    int jb = (threadIdx.x & 7) * 4;
    int n  = blockIdx.x * 32 + (threadIdx.x >> 3);
    if (n >= N) return;

    const float4 hv = *(const float4*)(H + (size_t)n * HID + jb);
    float p = hv.x * lw[jb] + hv.y * lw[jb + 1] + hv.z * lw[jb + 2] + hv.w * lw[jb + 3];
    p += __shfl_xor(p, 1, 8);
    p += __shfl_xor(p, 2, 8);
    p += __shfl_xor(p, 4, 8);
    if ((threadIdx.x & 7) == 0) s3[n] = p * dinv[n];
}

// ======================= aggregation (gather, fp16 messages -> f32 accum) =======================

__global__ __launch_bounds__(256) void k_gather32(const int* __restrict__ rowptr,
                                                  const int* __restrict__ deg,
                                                  const int* __restrict__ csr,
                                                  const float* __restrict__ Bm,
                                                  const float* __restrict__ dinv,
                                                  const float* __restrict__ bias,
                                                  float* __restrict__ H, int N, int relu) {
    int lane = threadIdx.x & 7;
    int n    = blockIdx.x * 32 + (threadIdx.x >> 3);
    if (n >= N) return;

    const float2* B2 = (const float2*)Bm;
    hpack u0; u0.f2 = B2[(size_t)n * 8 + lane];     // self-loop term
    float2 l0 = __half22float2(u0.h2[0]);
    float2 l1 = __half22float2(u0.h2[1]);
    float4 acc = make_float4(l0.x, l0.y, l1.x, l1.y);

    int s = rowptr[n], cnt = deg[n];
    int k = 0;
    for (; k + 3 < cnt; k += 4) {
        int r0 = csr[s + k],     r1 = csr[s + k + 1];
        int r2 = csr[s + k + 2], r3 = csr[s + k + 3];
        hpack p0, p1, p2, p3;
        p0.f2 = B2[(size_t)r0 * 8 + lane];
        p1.f2 = B2[(size_t)r1 * 8 + lane];
        p2.f2 = B2[(size_t)r2 * 8 + lane];
        p3.f2 = B2[(size_t)r3 * 8 + lane];
        float2 a0 = __half22float2(p0.h2[0]), b0 = __half22float2(p0.h2[1]);
        float2 a1 = __half22float2(p1.h2[0]), b1 = __half22float2(p1.h2[1]);
        float2 a2 = __half22float2(p2.h2[0]), b2 = __half22float2(p2.h2[1]);
        float2 a3 = __half22float2(p3.h2[0]), b3 = __half22float2(p3.h2[1]);
        acc.x += (a0.x + a1.x) + (a2.x + a3.x);
        acc.y += (a0.y + a1.y) + (a2.y + a3.y);
        acc.z += (b0.x + b1.x) + (b2.x + b3.x);
        acc.w += (b0.y + b1.y) + (b2.y + b3.y);
    }
    for (; k < cnt; ++k) {
        hpack p; p.f2 = B2[(size_t)csr[s + k] * 8 + lane];
        float2 a = __half22float2(p.h2[0]), b = __half22float2(p.h2[1]);
        acc.x += a.x; acc.y += a.y; acc.z += b.x; acc.w += b.y;
    }
    float dv = dinv[n];
    float4 b4 = ((const float4*)bias)[lane];
    float4 o;
    o.x = fmaf(dv, acc.x, b4.x);
    o.y = fmaf(dv, acc.y, b4.y);
    o.z = fmaf(dv, acc.z, b4.z);
    o.w = fmaf(dv, acc.w, b4.w);
    if (relu) {
        o.x = fmaxf(o.x, 0.f); o.y = fmaxf(o.y, 0.f);
        o.z = fmaxf(o.z, 0.f); o.w = fmaxf(o.w, 0.f);
    }
    ((float4*)H)[(size_t)n * 8 + lane] = o;
}

__global__ __launch_bounds__(256) void k_gather1(const int* __restrict__ rowptr,
                                                 const int* __restrict__ deg,
                                                 const int* __restrict__ csr,
                                                 const float* __restrict__ s3,
                                                 const float* __restrict__ dinv,
                                                 const float* __restrict__ b3,
                                                 float* __restrict__ out, int N) {
    int lane = threadIdx.x & 7;
    int n    = blockIdx.x * 32 + (threadIdx.x >> 3);
    if (n >= N) return;

    int s = rowptr[n], cnt = deg[n];
    float acc = 0.f;
    for (int k = lane; k < cnt; k += 8) acc += s3[csr[s + k]];
    acc += __shfl_xor(acc, 1, 8);
    acc += __shfl_xor(acc, 2, 8);
    acc += __shfl_xor(acc, 4, 8);
    if (lane == 0) out[n] = fmaf(dinv[n], acc + s3[n], b3[0]);
}

// ======================= host launch =======================

static inline size_t align64(size_t x) { return (x + 63) & ~(size_t)63; }

extern "C" void kernel_launch(void* const* d_in, const int* in_sizes, int n_in,
                              void* d_out, int out_size, void* d_ws, size_t ws_size,
                              hipStream_t stream) {
    const float* x   = (const float*)d_in[0];
    const int*   ei  = (const int*)d_in[1];   // jax x64 disabled -> int32
    const float* W1  = (const float*)d_in[2];
    const float* b1  = (const float*)d_in[3];
    const float* W2  = (const float*)d_in[4];
    const float* b2  = (const float*)d_in[5];
    const float* W3  = (const float*)d_in[6];
    const float* b3  = (const float*)d_in[7];

    const int N = in_sizes[0] / IN_DIM;       // 100000
    const int E = in_sizes[1] / 2;            // 2400000
    const int* row = ei;                       // message source
    const int* col = ei + E;                   // aggregation target

    // workspace layout (64B-aligned regions)
    char* p = (char*)d_ws;
    size_t off = 0;
    float* dinv   = (float*)(p + off); off = align64(off + (size_t)N * 4);
    float* B      = (float*)(p + off); off = align64(off + (size_t)N * HID * 4);
    float* H      = (float*)(p + off); off = align64(off + (size_t)N * HID * 4);
    int*   deg    = (int*)  (p + off); off = align64(off + (size_t)N * 4);
    int*   rowptr = (int*)  (p + off); off = align64(off + (size_t)N * 4);
    int*   ghist  = (int*)  (p + off); off = align64(off + 256 * 4);
    int*   gbase  = (int*)  (p + off); off = align64(off + 320 * 4);
    int*   cursor = (int*)  (p + off); off = align64(off + 256 * 4);
    int*   csr    = (int*)  (p + off); off = align64(off + (size_t)E * 4);
    float* out    = (float*)d_out;

    // bcol/brow live in the B/H regions (CSR build completes before B/H are used)
    int* bcol = (int*)B;   // E*4 = 9.6MB <= 12.8MB
    int* brow = (int*)H;

    const int gBuild = (E + CHUNK - 1) / CHUNK;   // 586
    const int NB     = (N + BSIZE - 1) / BSIZE;   // 196
    const int gNode  = (N + 31) / 32;             // 32 nodes/block kernels

    // ---- CSR build + normalization ----
    hipMemsetAsync(ghist, 0, 256 * 4, stream);
    kA_hist   <<<gBuild, 256,  0, stream>>>(col, ghist, E);
    kA_scan   <<<1,      256,  0, stream>>>(ghist, gbase, cursor);
    kB_scatter<<<gBuild, 256,  0, stream>>>(row, col, cursor, bcol, brow, E);
    kC_fill   <<<NB,     1024, 0, stream>>>(bcol, brow, gbase, csr, rowptr, deg, dinv, N);

    // ---- layer 1 ----
    k_xform1  <<<gNode, 256, 0, stream>>>(x, W1, dinv, B, N);
    k_gather32<<<gNode, 256, 0, stream>>>(rowptr, deg, csr, B, dinv, b1, H, N, 1);

    // ---- layer 2 ----
    k_xform2  <<<gNode, 256, 0, stream>>>(H, W2, dinv, B, N);
    k_gather32<<<gNode, 256, 0, stream>>>(rowptr, deg, csr, B, dinv, b2, H, N, 1);

    // ---- layer 3 ----
    k_xform3  <<<gNode, 256, 0, stream>>>(H, W3, dinv, B, N);   // s3 in B (f32)
    k_gather1 <<<gNode, 256, 0, stream>>>(rowptr, deg, csr, B, dinv, b3, out, N);
}

// Round 8
// 164.467 us; speedup vs baseline: 4.9535x; 1.1775x over previous
//
#include <hip/hip_runtime.h>
#include <hip/hip_fp16.h>

#define IN_DIM 128
#define HID    32
#define CHUNK  4096      // edges per block in CSR-build kernels
#define BSH    9         // log2(nodes per bucket)
#define BSIZE  512       // nodes per bucket
#define CAPSH  14        // per-bucket slot capacity = 16384 (mean 12245 + 37 sigma)

typedef union { float2 f2; __half2 h2[2]; } hpack;

// ======================= CSR build (fixed-capacity buckets, no global pre-scan) =======================

// cursor[b] = b * CAP; one tiny block replaces kA_hist + kA_scan + memset.
__global__ void k_init_cursor(int* __restrict__ cursor) {
    cursor[threadIdx.x] = threadIdx.x << CAPSH;
}

// kB: per-block LDS counting sort by bucket, contiguous reservation via cursor,
// coalesced run writes into fixed-capacity bucket regions.
__global__ __launch_bounds__(256) void kB_scatter(const int* __restrict__ row,
                                                  const int* __restrict__ col,
                                                  int* __restrict__ cursor,
                                                  int* __restrict__ bcol,
                                                  int* __restrict__ brow, int E) {
    __shared__ int lh[256];      // per-bucket counts (preserved)
    __shared__ int ls[256];      // exclusive local starts
    __shared__ int gdst[256];    // global_base - local_start per bucket
    __shared__ int c2[256];      // local rank cursors
    __shared__ int sc[CHUNK];    // bucket-sorted cols
    __shared__ int sr[CHUNK];    // bucket-sorted rows
    int tid = threadIdx.x;
    lh[tid] = 0; c2[tid] = 0;
    __syncthreads();

    int base = blockIdx.x * CHUNK;
    int nE = min(CHUNK, E - base);

    // 1) local bucket histogram
    for (int i = tid; i < nE; i += 256)
        atomicAdd(&lh[col[base + i] >> BSH], 1);
    __syncthreads();

    // 2) exclusive scan of local counts
    int v = lh[tid];
    ls[tid] = v;
    __syncthreads();
    for (int off = 1; off < 256; off <<= 1) {
        int nv = ls[tid] + (tid >= off ? ls[tid - off] : 0);
        __syncthreads();
        ls[tid] = nv;
        __syncthreads();
    }
    ls[tid] -= v;                 // exclusive
    __syncthreads();

    // 3) reserve contiguous space per non-empty bucket (rotate to spread cursors)
    int bb = (tid + blockIdx.x) & 255;
    int vb = lh[bb];
    if (vb) gdst[bb] = atomicAdd(&cursor[bb], vb) - ls[bb];
    __syncthreads();

    // 4) LDS counting-sort scatter
    for (int i = tid; i < nE; i += 256) {
        int c = col[base + i];
        int r = row[base + i];
        int b = c >> BSH;
        int k = atomicAdd(&c2[b], 1);
        int idx = ls[b] + k;
        sc[idx] = c;
        sr[idx] = r;
    }
    __syncthreads();

    // 5) write bucket-sorted runs to global (consecutive lanes -> consecutive dst)
    for (int i = tid; i < nE; i += 256) {
        int c = sc[i];
        int b = c >> BSH;
        int d = gdst[b] + i;
        bcol[d] = c;
        brow[d] = sr[i];
    }
}

// kC: one 1024-thread block per bucket. Bucket data in [b<<CAPSH, cursor[b]).
// Produces deg, rowptr, dinv, csr.
__global__ __launch_bounds__(1024) void kC_fill(const int* __restrict__ bcol,
                                                const int* __restrict__ brow,
                                                const int* __restrict__ cursor,
                                                int* __restrict__ csr,
                                                int* __restrict__ rowptr,
                                                int* __restrict__ deg,
                                                float* __restrict__ dinv, int N) {
    __shared__ int cnt[BSIZE], ex[BSIZE], c2[BSIZE];
    int tid = threadIdx.x;
    int b = blockIdx.x;
    int s = b << CAPSH;
    int e = cursor[b];
    int c0 = b << BSH;

    if (tid < BSIZE) { cnt[tid] = 0; c2[tid] = 0; }
    __syncthreads();

    // 1) local degree histogram
    for (int i = s + tid; i < e; i += 1024)
        atomicAdd(&cnt[bcol[i] - c0], 1);
    __syncthreads();

    // 2) inclusive scan of 512 counts (threads 0..511 active)
    if (tid < BSIZE) ex[tid] = cnt[tid];
    __syncthreads();
    for (int off = 1; off < BSIZE; off <<= 1) {
        int nv = 0;
        if (tid < BSIZE) nv = ex[tid] + (tid >= off ? ex[tid - off] : 0);
        __syncthreads();
        if (tid < BSIZE) ex[tid] = nv;
        __syncthreads();
    }

    // 3) to exclusive; emit rowptr / deg / dinv
    if (tid < BSIZE) {
        int ev = ex[tid] - cnt[tid];
        ex[tid] = ev;
        int n = c0 + tid;
        if (n < N) {
            rowptr[n] = s + ev;
            deg[n]    = cnt[tid];
            dinv[n]   = rsqrtf((float)cnt[tid] + 1.0f);
        }
    }
    __syncthreads();

    // 4) fill csr (writes land within this bucket's ~64KB window)
    for (int i = s + tid; i < e; i += 1024) {
        int c = bcol[i] - c0;
        int k = atomicAdd(&c2[c], 1);
        csr[s + ex[c] + k] = brow[i];
    }
}

// ======================= layer 1 transform: s1 = dinv * (x @ W1), fp16 out =======================

__global__ __launch_bounds__(256) void k_xform1(const float* __restrict__ x,
                                                const float* __restrict__ W,
                                                const float* __restrict__ dinv,
                                                float* __restrict__ B, int N) {
    __shared__ float lw[IN_DIM * HID];
    for (int i = threadIdx.x; i < IN_DIM * HID; i += 256) lw[i] = W[i];
    __syncthreads();

    int lane = threadIdx.x & 7;
    int jb = lane * 4;
    int n  = blockIdx.x * 32 + (threadIdx.x >> 3);
    if (n >= N) return;

    const float* xr = x + (size_t)n * IN_DIM;
    float a0 = 0.f, a1 = 0.f, a2 = 0.f, a3 = 0.f;
    #pragma unroll 8
    for (int k = 0; k < IN_DIM; ++k) {
        float xv = xr[k];
        const float* wp = &lw[k * HID + jb];
        a0 = fmaf(xv, wp[0], a0);
        a1 = fmaf(xv, wp[1], a1);
        a2 = fmaf(xv, wp[2], a2);
        a3 = fmaf(xv, wp[3], a3);
    }
    float dv = dinv[n];
    hpack u;
    u.h2[0] = __floats2half2_rn(a0 * dv, a1 * dv);
    u.h2[1] = __floats2half2_rn(a2 * dv, a3 * dv);
    ((float2*)B)[(size_t)n * 8 + lane] = u.f2;
}

// ======================= fused gather + transform kernels =======================
// Gather fp16 messages with f32 accum, apply dinv/bias/relu -> full H row lives in
// the 8-lane group's registers; immediately apply the next weight via shuffles.

// gather(B0) -> h1 = relu(...) -> s2 = dinv * (h1 @ W2), fp16 out. H never stored.
__global__ __launch_bounds__(256) void k_gxf2(const int* __restrict__ rowptr,
                                              const int* __restrict__ deg,
                                              const int* __restrict__ csr,
                                              const float* __restrict__ Bin,
                                              const float* __restrict__ dinv,
                                              const float* __restrict__ bias,
                                              const float* __restrict__ W2,
                                              float* __restrict__ Bout, int N) {
    __shared__ float lw[HID * HID];
    for (int i = threadIdx.x; i < HID * HID; i += 256) lw[i] = W2[i];
    __syncthreads();

    int lane = threadIdx.x & 7;
    int jb = lane * 4;
    int n  = blockIdx.x * 32 + (threadIdx.x >> 3);
    if (n >= N) return;

    const float2* B2 = (const float2*)Bin;
    hpack u0; u0.f2 = B2[(size_t)n * 8 + lane];     // self-loop term
    float2 l0 = __half22float2(u0.h2[0]);
    float2 l1 = __half22float2(u0.h2[1]);
    float4 acc = make_float4(l0.x, l0.y, l1.x, l1.y);

    int s = rowptr[n], cnt = deg[n];
    int k = 0;
    for (; k + 3 < cnt; k += 4) {
        int r0 = csr[s + k],     r1 = csr[s + k + 1];
        int r2 = csr[s + k + 2], r3 = csr[s + k + 3];
        hpack p0, p1, p2, p3;
        p0.f2 = B2[(size_t)r0 * 8 + lane];
        p1.f2 = B2[(size_t)r1 * 8 + lane];
        p2.f2 = B2[(size_t)r2 * 8 + lane];
        p3.f2 = B2[(size_t)r3 * 8 + lane];
        float2 a0 = __half22float2(p0.h2[0]), b0 = __half22float2(p0.h2[1]);
        float2 a1 = __half22float2(p1.h2[0]), b1 = __half22float2(p1.h2[1]);
        float2 a2 = __half22float2(p2.h2[0]), b2 = __half22float2(p2.h2[1]);
        float2 a3 = __half22float2(p3.h2[0]), b3 = __half22float2(p3.h2[1]);
        acc.x += (a0.x + a1.x) + (a2.x + a3.x);
        acc.y += (a0.y + a1.y) + (a2.y + a3.y);
        acc.z += (b0.x + b1.x) + (b2.x + b3.x);
        acc.w += (b0.y + b1.y) + (b2.y + b3.y);
    }
    for (; k < cnt; ++k) {
        hpack p; p.f2 = B2[(size_t)csr[s + k] * 8 + lane];
        float2 a = __half22float2(p.h2[0]), b = __half22float2(p.h2[1]);
        acc.x += a.x; acc.y += a.y; acc.z += b.x; acc.w += b.y;
    }
    float dv = dinv[n];
    float4 b4 = ((const float4*)bias)[lane];
    float4 o;
    o.x = fmaxf(fmaf(dv, acc.x, b4.x), 0.f);
    o.y = fmaxf(fmaf(dv, acc.y, b4.y), 0.f);
    o.z = fmaxf(fmaf(dv, acc.z, b4.z), 0.f);
    o.w = fmaxf(fmaf(dv, acc.w, b4.w), 0.f);

    // fused h1 @ W2 across the 8-lane group (h1[sl*4+j] = component j of lane sl)
    float t0 = 0.f, t1 = 0.f, t2 = 0.f, t3 = 0.f;
    #pragma unroll
    for (int sl = 0; sl < 8; ++sl) {
        float h0 = __shfl(o.x, sl, 8);
        float h1 = __shfl(o.y, sl, 8);
        float h2 = __shfl(o.z, sl, 8);
        float h3 = __shfl(o.w, sl, 8);
        const float* w0 = &lw[(sl * 4 + 0) * HID + jb];
        const float* w1 = &lw[(sl * 4 + 1) * HID + jb];
        const float* w2 = &lw[(sl * 4 + 2) * HID + jb];
        const float* w3 = &lw[(sl * 4 + 3) * HID + jb];
        t0 = fmaf(h0, w0[0], t0); t1 = fmaf(h0, w0[1], t1);
        t2 = fmaf(h0, w0[2], t2); t3 = fmaf(h0, w0[3], t3);
        t0 = fmaf(h1, w1[0], t0); t1 = fmaf(h1, w1[1], t1);
        t2 = fmaf(h1, w1[2], t2); t3 = fmaf(h1, w1[3], t3);
        t0 = fmaf(h2, w2[0], t0); t1 = fmaf(h2, w2[1], t1);
        t2 = fmaf(h2, w2[2], t2); t3 = fmaf(h2, w2[3], t3);
        t0 = fmaf(h3, w3[0], t0); t1 = fmaf(h3, w3[1], t1);
        t2 = fmaf(h3, w3[2], t2); t3 = fmaf(h3, w3[3], t3);
    }
    hpack w;
    w.h2[0] = __floats2half2_rn(t0 * dv, t1 * dv);
    w.h2[1] = __floats2half2_rn(t2 * dv, t3 * dv);
    ((float2*)Bout)[(size_t)n * 8 + lane] = w.f2;
}

// gather(B1) -> h2 = relu(...) -> s3 = dinv * (h2 . W3), f32 scalar out.
__global__ __launch_bounds__(256) void k_gxf3(const int* __restrict__ rowptr,
                                              const int* __restrict__ deg,
                                              const int* __restrict__ csr,
                                              const float* __restrict__ Bin,
                                              const float* __restrict__ dinv,
                                              const float* __restrict__ bias,
                                              const float* __restrict__ W3,
                                              float* __restrict__ s3, int N) {
    __shared__ float lw[HID];
    if (threadIdx.x < HID) lw[threadIdx.x] = W3[threadIdx.x];
    __syncthreads();

    int lane = threadIdx.x & 7;
    int jb = lane * 4;
    int n  = blockIdx.x * 32 + (threadIdx.x >> 3);
    if (n >= N) return;

    const float2* B2 = (const float2*)Bin;
    hpack u0; u0.f2 = B2[(size_t)n * 8 + lane];
    float2 l0 = __half22float2(u0.h2[0]);
    float2 l1 = __half22float2(u0.h2[1]);
    float4 acc = make_float4(l0.x, l0.y, l1.x, l1.y);

    int s = rowptr[n], cnt = deg[n];
    int k = 0;
    for (; k + 3 < cnt; k += 4) {
        int r0 = csr[s + k],     r1 = csr[s + k + 1];
        int r2 = csr[s + k + 2], r3 = csr[s + k + 3];
        hpack p0, p1, p2, p3;
        p0.f2 = B2[(size_t)r0 * 8 + lane];
        p1.f2 = B2[(size_t)r1 * 8 + lane];
        p2.f2 = B2[(size_t)r2 * 8 + lane];
        p3.f2 = B2[(size_t)r3 * 8 + lane];
        float2 a0 = __half22float2(p0.h2[0]), b0 = __half22float2(p0.h2[1]);
        float2 a1 = __half22float2(p1.h2[0]), b1 = __half22float2(p1.h2[1]);
        float2 a2 = __half22float2(p2.h2[0]), b2 = __half22float2(p2.h2[1]);
        float2 a3 = __half22float2(p3.h2[0]), b3 = __half22float2(p3.h2[1]);
        acc.x += (a0.x + a1.x) + (a2.x + a3.x);
        acc.y += (a0.y + a1.y) + (a2.y + a3.y);
        acc.z += (b0.x + b1.x) + (b2.x + b3.x);
        acc.w += (b0.y + b1.y) + (b2.y + b3.y);
    }
    for (; k < cnt; ++k) {
        hpack p; p.f2 = B2[(size_t)csr[s + k] * 8 + lane];
        float2 a = __half22float2(p.h2[0]), b = __half22float2(p.h2[1]);
        acc.x += a.x; acc.y += a.y; acc.z += b.x; acc.w += b.y;
    }
    float dv = dinv[n];
    float4 b4 = ((const float4*)bias)[lane];
    float4 o;
    o.x = fmaxf(fmaf(dv, acc.x, b4.x), 0.f);
    o.y = fmaxf(fmaf(dv, acc.y, b4.y), 0.f);
    o.z = fmaxf(fmaf(dv, acc.z, b4.z), 0.f);
    o.w = fmaxf(fmaf(dv, acc.w, b4.w), 0.f);

    float p = o.x * lw[jb] + o.y * lw[jb + 1] + o.z * lw[jb + 2] + o.w * lw[jb + 3];
    p += __shfl_xor(p, 1, 8);
    p += __shfl_xor(p, 2, 8);
    p += __shfl_xor(p, 4, 8);
    if (lane == 0) s3[n] = p * dv;
}

// out[n] = dinv[n] * (s3[n] + sum_nbrs s3[r]) + b3 ; 8 lanes/node strided.
__global__ __launch_bounds__(256) void k_gather1(const int* __restrict__ rowptr,
                                                 const int* __restrict__ deg,
                                                 const int* __restrict__ csr,
                                                 const float* __restrict__ s3,
                                                 const float* __restrict__ dinv,
                                                 const float* __restrict__ b3,
                                                 float* __restrict__ out, int N) {
    int lane = threadIdx.x & 7;
    int n    = blockIdx.x * 32 + (threadIdx.x >> 3);
    if (n >= N) return;

    int s = rowptr[n], cnt = deg[n];
    float acc = 0.f;
    for (int k = lane; k < cnt; k += 8) acc += s3[csr[s + k]];
    acc += __shfl_xor(acc, 1, 8);
    acc += __shfl_xor(acc, 2, 8);
    acc += __shfl_xor(acc, 4, 8);
    if (lane == 0) out[n] = fmaf(dinv[n], acc + s3[n], b3[0]);
}

// ======================= host launch =======================

static inline size_t align64(size_t x) { return (x + 63) & ~(size_t)63; }

extern "C" void kernel_launch(void* const* d_in, const int* in_sizes, int n_in,
                              void* d_out, int out_size, void* d_ws, size_t ws_size,
                              hipStream_t stream) {
    const float* x   = (const float*)d_in[0];
    const int*   ei  = (const int*)d_in[1];   // jax x64 disabled -> int32
    const float* W1  = (const float*)d_in[2];
    const float* b1  = (const float*)d_in[3];
    const float* W2  = (const float*)d_in[4];
    const float* b2  = (const float*)d_in[5];
    const float* W3  = (const float*)d_in[6];
    const float* b3  = (const float*)d_in[7];

    const int N = in_sizes[0] / IN_DIM;       // 100000
    const int E = in_sizes[1] / 2;            // 2400000
    const int* row = ei;                       // message source
    const int* col = ei + E;                   // aggregation target

    const int NB = (N + BSIZE - 1) / BSIZE;    // 196 buckets
    const size_t bktCap = (size_t)NB << CAPSH; // padded slot count

    // workspace layout (64B-aligned regions)
    char* p = (char*)d_ws;
    size_t off = 0;
    float* dinv   = (float*)(p + off); off = align64(off + (size_t)N * 4);
    float* B0     = (float*)(p + off); off = align64(off + (size_t)N * HID * 2);  // fp16 msgs
    float* B1     = (float*)(p + off); off = align64(off + (size_t)N * HID * 2);  // fp16 msgs
    float* s3     = (float*)(p + off); off = align64(off + (size_t)N * 4);
    int*   deg    = (int*)  (p + off); off = align64(off + (size_t)N * 4);
    int*   rowptr = (int*)  (p + off); off = align64(off + (size_t)N * 4);
    int*   cursor = (int*)  (p + off); off = align64(off + 256 * 4);
    int*   bcol   = (int*)  (p + off); off = align64(off + bktCap * 4);
    int*   brow   = (int*)  (p + off); off = align64(off + bktCap * 4);
    int*   csr    = (int*)  (p + off); off = align64(off + bktCap * 4);
    float* out    = (float*)d_out;

    const int gBuild = (E + CHUNK - 1) / CHUNK;   // 586
    const int gNode  = (N + 31) / 32;             // 3125

    // ---- CSR build + normalization (fixed-capacity buckets) ----
    k_init_cursor<<<1,      256,  0, stream>>>(cursor);
    kB_scatter   <<<gBuild, 256,  0, stream>>>(row, col, cursor, bcol, brow, E);
    kC_fill      <<<NB,     1024, 0, stream>>>(bcol, brow, cursor, csr, rowptr, deg, dinv, N);

    // ---- fused 3-layer GCN ----
    k_xform1 <<<gNode, 256, 0, stream>>>(x, W1, dinv, B0, N);
    k_gxf2   <<<gNode, 256, 0, stream>>>(rowptr, deg, csr, B0, dinv, b1, W2, B1, N);
    k_gxf3   <<<gNode, 256, 0, stream>>>(rowptr, deg, csr, B1, dinv, b2, W3, s3, N);
    k_gather1<<<gNode, 256, 0, stream>>>(rowptr, deg, csr, s3, dinv, b3, out, N);
}

// Round 9
// 157.299 us; speedup vs baseline: 5.1792x; 1.0456x over previous
//
#include <hip/hip_runtime.h>
#include <hip/hip_fp16.h>

#define IN_DIM 128
#define HID    32
#define CHUNK  4096      // edges per block in kB
#define BSH    9         // log2(nodes per bucket)
#define BSIZE  512       // nodes per bucket
#define CAPSH  14        // per-bucket slot capacity = 16384 (mean 12245 + 37 sigma)
#define ROWBITS 17       // N = 100000 < 2^17

typedef union { float2 f2; __half2 h2[2]; } hpack;

// ======================= CSR build (fixed-capacity buckets, packed edges) =======================

// cursor[b] = b * CAP
__global__ void k_init_cursor(int* __restrict__ cursor) {
    cursor[threadIdx.x] = threadIdx.x << CAPSH;
}

// kB: 512 threads; LDS counting sort by bucket; writes ONE packed int per edge:
// (local_col<<17)|row. 24KB LDS.
__global__ __launch_bounds__(512) void kB_scatter(const int* __restrict__ row,
                                                  const int* __restrict__ col,
                                                  int* __restrict__ cursor,
                                                  int* __restrict__ bpack, int E) {
    __shared__ int lh[256];            // per-bucket counts (preserved)
    __shared__ int ls[256];            // exclusive local starts
    __shared__ int gdst[256];          // global_base - local_start per bucket
    __shared__ int c2[256];            // local rank cursors
    __shared__ int sp[CHUNK];          // bucket-sorted packed edges
    __shared__ unsigned char sb[CHUNK];// bucket id per slot (for writeout)
    int tid = threadIdx.x;
    if (tid < 256) { lh[tid] = 0; c2[tid] = 0; }
    __syncthreads();

    int base = blockIdx.x * CHUNK;
    int nE = min(CHUNK, E - base);

    // 1) local bucket histogram
    for (int i = tid; i < nE; i += 512)
        atomicAdd(&lh[col[base + i] >> BSH], 1);
    __syncthreads();

    // 2) exclusive scan of local counts (threads 0..255)
    int v = 0;
    if (tid < 256) { v = lh[tid]; ls[tid] = v; }
    __syncthreads();
    for (int off = 1; off < 256; off <<= 1) {
        int nv = 0;
        if (tid < 256) nv = ls[tid] + (tid >= off ? ls[tid - off] : 0);
        __syncthreads();
        if (tid < 256) ls[tid] = nv;
        __syncthreads();
    }
    if (tid < 256) ls[tid] -= v;
    __syncthreads();

    // 3) reserve contiguous space per non-empty bucket (rotate to spread cursors)
    if (tid < 256) {
        int bb = (tid + blockIdx.x) & 255;
        int vb = lh[bb];
        if (vb) gdst[bb] = atomicAdd(&cursor[bb], vb) - ls[bb];
    }
    __syncthreads();

    // 4) LDS counting-sort scatter (pack lc|row)
    for (int i = tid; i < nE; i += 512) {
        int c = col[base + i];
        int r = row[base + i];
        int b = c >> BSH;
        int k = atomicAdd(&c2[b], 1);
        int idx = ls[b] + k;
        sp[idx] = ((c & (BSIZE - 1)) << ROWBITS) | r;
        sb[idx] = (unsigned char)b;
    }
    __syncthreads();

    // 5) write bucket-sorted runs to global (consecutive lanes -> consecutive dst)
    for (int i = tid; i < nE; i += 512) {
        int b = sb[i];
        bpack[gdst[b] + i] = sp[i];
    }
}

// kC: one 1024-thread block per bucket; stage packed edges in LDS once,
// then histogram + scan + fill entirely from LDS. Produces deg/rowptr/dinv/csr.
__global__ __launch_bounds__(1024) void kC_fill(const int* __restrict__ bpack,
                                                const int* __restrict__ cursor,
                                                int* __restrict__ csr,
                                                int* __restrict__ rowptr,
                                                int* __restrict__ deg,
                                                float* __restrict__ dinv, int N) {
    __shared__ int cnt[BSIZE], ex[BSIZE], c2[BSIZE];
    __shared__ int sp[1 << CAPSH];     // 64 KB staged bucket edges
    int tid = threadIdx.x;
    int b = blockIdx.x;
    int s = b << CAPSH;
    int ne = cursor[b] - s;
    int c0 = b << BSH;

    if (tid < BSIZE) { cnt[tid] = 0; c2[tid] = 0; }
    __syncthreads();

    // 1) stage + degree histogram
    for (int i = tid; i < ne; i += 1024) {
        int v = bpack[s + i];
        sp[i] = v;
        atomicAdd(&cnt[v >> ROWBITS], 1);
    }
    __syncthreads();

    // 2) inclusive scan of 512 counts (threads 0..511)
    if (tid < BSIZE) ex[tid] = cnt[tid];
    __syncthreads();
    for (int off = 1; off < BSIZE; off <<= 1) {
        int nv = 0;
        if (tid < BSIZE) nv = ex[tid] + (tid >= off ? ex[tid - off] : 0);
        __syncthreads();
        if (tid < BSIZE) ex[tid] = nv;
        __syncthreads();
    }

    // 3) to exclusive; emit rowptr / deg / dinv
    if (tid < BSIZE) {
        int ev = ex[tid] - cnt[tid];
        ex[tid] = ev;
        int n = c0 + tid;
        if (n < N) {
            rowptr[n] = s + ev;
            deg[n]    = cnt[tid];
            dinv[n]   = rsqrtf((float)cnt[tid] + 1.0f);
        }
    }
    __syncthreads();

    // 4) fill csr from LDS (writes land within this bucket's 64KB window)
    for (int i = tid; i < ne; i += 1024) {
        int v = sp[i];
        int c = v >> ROWBITS;
        int k = atomicAdd(&c2[c], 1);
        csr[s + ex[c] + k] = v & ((1 << ROWBITS) - 1);
    }
}

// ======================= layer 1 transform: s1 = dinv * (x @ W1), fp16 out =======================

__global__ __launch_bounds__(256) void k_xform1(const float* __restrict__ x,
                                                const float* __restrict__ W,
                                                const float* __restrict__ dinv,
                                                float* __restrict__ B, int N) {
    __shared__ float lw[IN_DIM * HID];
    for (int i = threadIdx.x; i < IN_DIM * HID; i += 256) lw[i] = W[i];
    __syncthreads();

    int lane = threadIdx.x & 7;
    int jb = lane * 4;
    int n  = blockIdx.x * 32 + (threadIdx.x >> 3);
    if (n >= N) return;

    const float* xr = x + (size_t)n * IN_DIM;
    float a0 = 0.f, a1 = 0.f, a2 = 0.f, a3 = 0.f;
    #pragma unroll 8
    for (int k = 0; k < IN_DIM; ++k) {
        float xv = xr[k];
        const float* wp = &lw[k * HID + jb];
        a0 = fmaf(xv, wp[0], a0);
        a1 = fmaf(xv, wp[1], a1);
        a2 = fmaf(xv, wp[2], a2);
        a3 = fmaf(xv, wp[3], a3);
    }
    float dv = dinv[n];
    hpack u;
    u.h2[0] = __floats2half2_rn(a0 * dv, a1 * dv);
    u.h2[1] = __floats2half2_rn(a2 * dv, a3 * dv);
    ((float2*)B)[(size_t)n * 8 + lane] = u.f2;
}

// ======================= fused gather + transform kernels =======================

// gather(B0) -> h1 = relu(...) -> s2 = dinv * (h1 @ W2), fp16 out. H never stored.
__global__ __launch_bounds__(256) void k_gxf2(const int* __restrict__ rowptr,
                                              const int* __restrict__ deg,
                                              const int* __restrict__ csr,
                                              const float* __restrict__ Bin,
                                              const float* __restrict__ dinv,
                                              const float* __restrict__ bias,
                                              const float* __restrict__ W2,
                                              float* __restrict__ Bout, int N) {
    __shared__ float lw[HID * HID];
    for (int i = threadIdx.x; i < HID * HID; i += 256) lw[i] = W2[i];
    __syncthreads();

    int lane = threadIdx.x & 7;
    int jb = lane * 4;
    int n  = blockIdx.x * 32 + (threadIdx.x >> 3);
    if (n >= N) return;

    const float2* B2 = (const float2*)Bin;
    hpack u0; u0.f2 = B2[(size_t)n * 8 + lane];     // self-loop term
    float2 l0 = __half22float2(u0.h2[0]);
    float2 l1 = __half22float2(u0.h2[1]);
    float4 acc = make_float4(l0.x, l0.y, l1.x, l1.y);

    int s = rowptr[n], cnt = deg[n];
    int k = 0;
    for (; k + 3 < cnt; k += 4) {
        int r0 = csr[s + k],     r1 = csr[s + k + 1];
        int r2 = csr[s + k + 2], r3 = csr[s + k + 3];
        hpack p0, p1, p2, p3;
        p0.f2 = B2[(size_t)r0 * 8 + lane];
        p1.f2 = B2[(size_t)r1 * 8 + lane];
        p2.f2 = B2[(size_t)r2 * 8 + lane];
        p3.f2 = B2[(size_t)r3 * 8 + lane];
        float2 a0 = __half22float2(p0.h2[0]), b0 = __half22float2(p0.h2[1]);
        float2 a1 = __half22float2(p1.h2[0]), b1 = __half22float2(p1.h2[1]);
        float2 a2 = __half22float2(p2.h2[0]), b2 = __half22float2(p2.h2[1]);
        float2 a3 = __half22float2(p3.h2[0]), b3 = __half22float2(p3.h2[1]);
        acc.x += (a0.x + a1.x) + (a2.x + a3.x);
        acc.y += (a0.y + a1.y) + (a2.y + a3.y);
        acc.z += (b0.x + b1.x) + (b2.x + b3.x);
        acc.w += (b0.y + b1.y) + (b2.y + b3.y);
    }
    for (; k < cnt; ++k) {
        hpack p; p.f2 = B2[(size_t)csr[s + k] * 8 + lane];
        float2 a = __half22float2(p.h2[0]), b = __half22float2(p.h2[1]);
        acc.x += a.x; acc.y += a.y; acc.z += b.x; acc.w += b.y;
    }
    float dv = dinv[n];
    float4 b4 = ((const float4*)bias)[lane];
    float4 o;
    o.x = fmaxf(fmaf(dv, acc.x, b4.x), 0.f);
    o.y = fmaxf(fmaf(dv, acc.y, b4.y), 0.f);
    o.z = fmaxf(fmaf(dv, acc.z, b4.z), 0.f);
    o.w = fmaxf(fmaf(dv, acc.w, b4.w), 0.f);

    // fused h1 @ W2 across the 8-lane group (h1[sl*4+j] = component j of lane sl)
    float t0 = 0.f, t1 = 0.f, t2 = 0.f, t3 = 0.f;
    #pragma unroll
    for (int sl = 0; sl < 8; ++sl) {
        float h0 = __shfl(o.x, sl, 8);
        float h1 = __shfl(o.y, sl, 8);
        float h2 = __shfl(o.z, sl, 8);
        float h3 = __shfl(o.w, sl, 8);
        const float* w0 = &lw[(sl * 4 + 0) * HID + jb];
        const float* w1 = &lw[(sl * 4 + 1) * HID + jb];
        const float* w2 = &lw[(sl * 4 + 2) * HID + jb];
        const float* w3 = &lw[(sl * 4 + 3) * HID + jb];
        t0 = fmaf(h0, w0[0], t0); t1 = fmaf(h0, w0[1], t1);
        t2 = fmaf(h0, w0[2], t2); t3 = fmaf(h0, w0[3], t3);
        t0 = fmaf(h1, w1[0], t0); t1 = fmaf(h1, w1[1], t1);
        t2 = fmaf(h1, w1[2], t2); t3 = fmaf(h1, w1[3], t3);
        t0 = fmaf(h2, w2[0], t0); t1 = fmaf(h2, w2[1], t1);
        t2 = fmaf(h2, w2[2], t2); t3 = fmaf(h2, w2[3], t3);
        t0 = fmaf(h3, w3[0], t0); t1 = fmaf(h3, w3[1], t1);
        t2 = fmaf(h3, w3[2], t2); t3 = fmaf(h3, w3[3], t3);
    }
    hpack w;
    w.h2[0] = __floats2half2_rn(t0 * dv, t1 * dv);
    w.h2[1] = __floats2half2_rn(t2 * dv, t3 * dv);
    ((float2*)Bout)[(size_t)n * 8 + lane] = w.f2;
}

// gather(B1) -> h2 = relu(...) -> s3 = dinv * (h2 . W3), f32 scalar out.
__global__ __launch_bounds__(256) void k_gxf3(const int* __restrict__ rowptr,
                                              const int* __restrict__ deg,
                                              const int* __restrict__ csr,
                                              const float* __restrict__ Bin,
                                              const float* __restrict__ dinv,
                                              const float* __restrict__ bias,
                                              const float* __restrict__ W3,
                                              float* __restrict__ s3, int N) {
    __shared__ float lw[HID];
    if (threadIdx.x < HID) lw[threadIdx.x] = W3[threadIdx.x];
    __syncthreads();

    int lane = threadIdx.x & 7;
    int jb = lane * 4;
    int n  = blockIdx.x * 32 + (threadIdx.x >> 3);
    if (n >= N) return;

    const float2* B2 = (const float2*)Bin;
    hpack u0; u0.f2 = B2[(size_t)n * 8 + lane];
    float2 l0 = __half22float2(u0.h2[0]);
    float2 l1 = __half22float2(u0.h2[1]);
    float4 acc = make_float4(l0.x, l0.y, l1.x, l1.y);

    int s = rowptr[n], cnt = deg[n];
    int k = 0;
    for (; k + 3 < cnt; k += 4) {
        int r0 = csr[s + k],     r1 = csr[s + k + 1];
        int r2 = csr[s + k + 2], r3 = csr[s + k + 3];
        hpack p0, p1, p2, p3;
        p0.f2 = B2[(size_t)r0 * 8 + lane];
        p1.f2 = B2[(size_t)r1 * 8 + lane];
        p2.f2 = B2[(size_t)r2 * 8 + lane];
        p3.f2 = B2[(size_t)r3 * 8 + lane];
        float2 a0 = __half22float2(p0.h2[0]), b0 = __half22float2(p0.h2[1]);
        float2 a1 = __half22float2(p1.h2[0]), b1 = __half22float2(p1.h2[1]);
        float2 a2 = __half22float2(p2.h2[0]), b2 = __half22float2(p2.h2[1]);
        float2 a3 = __half22float2(p3.h2[0]), b3 = __half22float2(p3.h2[1]);
        acc.x += (a0.x + a1.x) + (a2.x + a3.x);
        acc.y += (a0.y + a1.y) + (a2.y + a3.y);
        acc.z += (b0.x + b1.x) + (b2.x + b3.x);
        acc.w += (b0.y + b1.y) + (b2.y + b3.y);
    }
    for (; k < cnt; ++k) {
        hpack p; p.f2 = B2[(size_t)csr[s + k] * 8 + lane];
        float2 a = __half22float2(p.h2[0]), b = __half22float2(p.h2[1]);
        acc.x += a.x; acc.y += a.y; acc.z += b.x; acc.w += b.y;
    }
    float dv = dinv[n];
    float4 b4 = ((const float4*)bias)[lane];
    float4 o;
    o.x = fmaxf(fmaf(dv, acc.x, b4.x), 0.f);
    o.y = fmaxf(fmaf(dv, acc.y, b4.y), 0.f);
    o.z = fmaxf(fmaf(dv, acc.z, b4.z), 0.f);
    o.w = fmaxf(fmaf(dv, acc.w, b4.w), 0.f);

    float p = o.x * lw[jb] + o.y * lw[jb + 1] + o.z * lw[jb + 2] + o.w * lw[jb + 3];
    p += __shfl_xor(p, 1, 8);
    p += __shfl_xor(p, 2, 8);
    p += __shfl_xor(p, 4, 8);
    if (lane == 0) s3[n] = p * dv;
}

// out[n] = dinv[n] * (s3[n] + sum_nbrs s3[r]) + b3 ; 8 lanes/node strided.
__global__ __launch_bounds__(256) void k_gather1(const int* __restrict__ rowptr,
                                                 const int* __restrict__ deg,
                                                 const int* __restrict__ csr,
                                                 const float* __restrict__ s3,
                                                 const float* __restrict__ dinv,
                                                 const float* __restrict__ b3,
                                                 float* __restrict__ out, int N) {
    int lane = threadIdx.x & 7;
    int n    = blockIdx.x * 32 + (threadIdx.x >> 3);
    if (n >= N) return;

    int s = rowptr[n], cnt = deg[n];
    float acc = 0.f;
    for (int k = lane; k < cnt; k += 8) acc += s3[csr[s + k]];
    acc += __shfl_xor(acc, 1, 8);
    acc += __shfl_xor(acc, 2, 8);
    acc += __shfl_xor(acc, 4, 8);
    if (lane == 0) out[n] = fmaf(dinv[n], acc + s3[n], b3[0]);
}

// ======================= host launch =======================

static inline size_t align64(size_t x) { return (x + 63) & ~(size_t)63; }

extern "C" void kernel_launch(void* const* d_in, const int* in_sizes, int n_in,
                              void* d_out, int out_size, void* d_ws, size_t ws_size,
                              hipStream_t stream) {
    const float* x   = (const float*)d_in[0];
    const int*   ei  = (const int*)d_in[1];   // jax x64 disabled -> int32
    const float* W1  = (const float*)d_in[2];
    const float* b1  = (const float*)d_in[3];
    const float* W2  = (const float*)d_in[4];
    const float* b2  = (const float*)d_in[5];
    const float* W3  = (const float*)d_in[6];
    const float* b3  = (const float*)d_in[7];

    const int N = in_sizes[0] / IN_DIM;       // 100000
    const int E = in_sizes[1] / 2;            // 2400000
    const int* row = ei;                       // message source
    const int* col = ei + E;                   // aggregation target

    const int NB = (N + BSIZE - 1) / BSIZE;    // 196 buckets
    const size_t bktCap = (size_t)NB << CAPSH; // padded slot count

    // workspace layout (64B-aligned regions)
    char* p = (char*)d_ws;
    size_t off = 0;
    float* dinv   = (float*)(p + off); off = align64(off + (size_t)N * 4);
    float* B0     = (float*)(p + off); off = align64(off + (size_t)N * HID * 2);  // fp16 msgs
    float* B1     = (float*)(p + off); off = align64(off + (size_t)N * HID * 2);  // fp16 msgs
    float* s3     = (float*)(p + off); off = align64(off + (size_t)N * 4);
    int*   deg    = (int*)  (p + off); off = align64(off + (size_t)N * 4);
    int*   rowptr = (int*)  (p + off); off = align64(off + (size_t)N * 4);
    int*   cursor = (int*)  (p + off); off = align64(off + 256 * 4);
    int*   bpack  = (int*)  (p + off); off = align64(off + bktCap * 4);
    int*   csr    = (int*)  (p + off); off = align64(off + bktCap * 4);
    float* out    = (float*)d_out;

    const int gBuild = (E + CHUNK - 1) / CHUNK;   // 586
    const int gNode  = (N + 31) / 32;             // 3125

    // ---- CSR build + normalization (fixed-capacity buckets, packed edges) ----
    k_init_cursor<<<1,      256,  0, stream>>>(cursor);
    kB_scatter   <<<gBuild, 512,  0, stream>>>(row, col, cursor, bpack, E);
    kC_fill      <<<NB,     1024, 0, stream>>>(bpack, cursor, csr, rowptr, deg, dinv, N);

    // ---- fused 3-layer GCN ----
    k_xform1 <<<gNode, 256, 0, stream>>>(x, W1, dinv, B0, N);
    k_gxf2   <<<gNode, 256, 0, stream>>>(rowptr, deg, csr, B0, dinv, b1, W2, B1, N);
    k_gxf3   <<<gNode, 256, 0, stream>>>(rowptr, deg, csr, B1, dinv, b2, W3, s3, N);
    k_gather1<<<gNode, 256, 0, stream>>>(rowptr, deg, csr, s3, dinv, b3, out, N);
}

// Round 11
// 143.976 us; speedup vs baseline: 5.6585x; 1.0925x over previous
//
#include <hip/hip_runtime.h>
#include <hip/hip_fp16.h>

#define IN_DIM 128
#define HID    32
#define CHUNK  4096      // edges per block in the build part
#define BSH    9         // log2(nodes per bucket)
#define BSIZE  512       // nodes per bucket
#define CAPSH  14        // per-bucket slot capacity = 16384 (mean 12245 + 37 sigma)
#define ROWBITS 17       // N = 100000 < 2^17

typedef union { float2 f2; __half2 h2[2]; } hpack;

// cursor[b] = b * CAP
__global__ void k_init_cursor(int* __restrict__ cursor) {
    cursor[threadIdx.x] = threadIdx.x << CAPSH;
}

// ======================= fused: bucket-sort (blocks < gBuild) + x@W1 (rest) =======================
// Build part: LDS counting sort by bucket, packed (lc<<17|row) writes.
// Xform part: t1 = x @ W1 (NO dinv — applied later in kC), fp16, 64 nodes/block.

__global__ __launch_bounds__(512) void k_fusedA(const int* __restrict__ row,
                                                const int* __restrict__ col,
                                                int* __restrict__ cursor,
                                                int* __restrict__ bpack,
                                                const float* __restrict__ x,
                                                const float* __restrict__ W1,
                                                float* __restrict__ T0,
                                                int E, int N, int gBuild) {
    __shared__ __align__(16) char smem[24576];
    int tid = threadIdx.x;

    if ((int)blockIdx.x < gBuild) {
        // ---- bucket counting sort ----
        int* lh   = (int*)smem;            // 256 counts (preserved)
        int* ls   = lh + 256;              // exclusive local starts
        int* gdst = ls + 256;              // global dst - local start
        int* c2   = gdst + 256;            // local rank cursors
        int* sp   = c2 + 256;              // CHUNK packed edges
        unsigned char* sb = (unsigned char*)(sp + CHUNK); // CHUNK bucket ids

        if (tid < 256) { lh[tid] = 0; c2[tid] = 0; }
        __syncthreads();

        int base = blockIdx.x * CHUNK;
        int nE = min(CHUNK, E - base);

        for (int i = tid; i < nE; i += 512)
            atomicAdd(&lh[col[base + i] >> BSH], 1);
        __syncthreads();

        int v = 0;
        if (tid < 256) { v = lh[tid]; ls[tid] = v; }
        __syncthreads();
        for (int off = 1; off < 256; off <<= 1) {
            int nv = 0;
            if (tid < 256) nv = ls[tid] + (tid >= off ? ls[tid - off] : 0);
            __syncthreads();
            if (tid < 256) ls[tid] = nv;
            __syncthreads();
        }
        if (tid < 256) ls[tid] -= v;
        __syncthreads();

        if (tid < 256) {
            int bb = (tid + blockIdx.x) & 255;
            int vb = lh[bb];
            if (vb) gdst[bb] = atomicAdd(&cursor[bb], vb) - ls[bb];
        }
        __syncthreads();

        for (int i = tid; i < nE; i += 512) {
            int c = col[base + i];
            int r = row[base + i];
            int b = c >> BSH;
            int k = atomicAdd(&c2[b], 1);
            int idx = ls[b] + k;
            sp[idx] = ((c & (BSIZE - 1)) << ROWBITS) | r;
            sb[idx] = (unsigned char)b;
        }
        __syncthreads();

        for (int i = tid; i < nE; i += 512) {
            int b = sb[i];
            bpack[gdst[b] + i] = sp[i];
        }
    } else {
        // ---- t1 = x @ W1 (unscaled), fp16 out ----
        float* lw = (float*)smem;          // 16 KB
        for (int i = tid; i < IN_DIM * HID; i += 512) lw[i] = W1[i];
        __syncthreads();

        int lane = tid & 7;
        int jb = lane * 4;
        int n  = (blockIdx.x - gBuild) * 64 + (tid >> 3);
        if (n >= N) return;

        const float* xr = x + (size_t)n * IN_DIM;
        float a0 = 0.f, a1 = 0.f, a2 = 0.f, a3 = 0.f;
        #pragma unroll 8
        for (int k = 0; k < IN_DIM; ++k) {
            float xv = xr[k];
            const float* wp = &lw[k * HID + jb];
            a0 = fmaf(xv, wp[0], a0);
            a1 = fmaf(xv, wp[1], a1);
            a2 = fmaf(xv, wp[2], a2);
            a3 = fmaf(xv, wp[3], a3);
        }
        hpack u;
        u.h2[0] = __floats2half2_rn(a0, a1);
        u.h2[1] = __floats2half2_rn(a2, a3);
        ((float2*)T0)[(size_t)n * 8 + lane] = u.f2;
    }
}

// ======================= kC: per-bucket CSR fill + deg/dinv + B0 scale =======================

__global__ __launch_bounds__(1024) void kC_fill(const int* __restrict__ bpack,
                                                const int* __restrict__ cursor,
                                                int* __restrict__ csr,
                                                int* __restrict__ rowptr,
                                                int* __restrict__ deg,
                                                float* __restrict__ dinv,
                                                float* __restrict__ B0, int N) {
    __shared__ int cnt[BSIZE], ex[BSIZE], c2[BSIZE];
    __shared__ int sp[1 << CAPSH];     // 64 KB staged bucket edges
    int tid = threadIdx.x;
    int b = blockIdx.x;
    int s = b << CAPSH;
    int ne = cursor[b] - s;
    int c0 = b << BSH;

    if (tid < BSIZE) { cnt[tid] = 0; c2[tid] = 0; }
    __syncthreads();

    // 1) stage + degree histogram
    for (int i = tid; i < ne; i += 1024) {
        int v = bpack[s + i];
        sp[i] = v;
        atomicAdd(&cnt[v >> ROWBITS], 1);
    }
    __syncthreads();

    // 2) inclusive scan of 512 counts
    if (tid < BSIZE) ex[tid] = cnt[tid];
    __syncthreads();
    for (int off = 1; off < BSIZE; off <<= 1) {
        int nv = 0;
        if (tid < BSIZE) nv = ex[tid] + (tid >= off ? ex[tid - off] : 0);
        __syncthreads();
        if (tid < BSIZE) ex[tid] = nv;
        __syncthreads();
    }

    // 3) to exclusive; emit rowptr / deg / dinv
    if (tid < BSIZE) {
        int ev = ex[tid] - cnt[tid];
        ex[tid] = ev;
        int n = c0 + tid;
        if (n < N) {
            rowptr[n] = s + ev;
            deg[n]    = cnt[tid];
            dinv[n]   = rsqrtf((float)cnt[tid] + 1.0f);
        }
    }
    __syncthreads();

    // 4) fill csr from LDS
    for (int i = tid; i < ne; i += 1024) {
        int v = sp[i];
        int c = v >> ROWBITS;
        int k = atomicAdd(&c2[c], 1);
        csr[s + ex[c] + k] = v & ((1 << ROWBITS) - 1);
    }

    // 5) scale T0 rows by dinv -> B0 in place.
    //    Row = 32 fp16 = 4 float4s; iterate float4 index j, node = j>>2, quad = j&3.
    for (int j = tid; j < BSIZE * 4; j += 1024) {
        int nl = j >> 2;
        int n = c0 + nl;
        if (n < N) {
            float dv = rsqrtf((float)cnt[nl] + 1.0f);
            union { float4 f4; __half2 h2[4]; } u;
            u.f4 = ((const float4*)B0)[(size_t)n * 4 + (j & 3)];
            #pragma unroll
            for (int q = 0; q < 4; ++q) {
                float2 f = __half22float2(u.h2[q]);
                u.h2[q] = __floats2half2_rn(f.x * dv, f.y * dv);
            }
            ((float4*)B0)[(size_t)n * 4 + (j & 3)] = u.f4;
        }
    }
}

// ======================= fused gather + transform kernels =======================

#define GLOAD(i, r) hpack p##i; p##i.f2 = B2[(size_t)(r) * 8 + lane]
#define GACC(i) { float2 a = __half22float2(p##i.h2[0]), b = __half22float2(p##i.h2[1]); \
                  acc.x += a.x; acc.y += a.y; acc.z += b.x; acc.w += b.y; }

// gather(B0) -> h1 = relu(...) -> s2 = dinv * (h1 @ W2), fp16 out. H never stored.
__global__ __launch_bounds__(256) void k_gxf2(const int* __restrict__ rowptr,
                                              const int* __restrict__ deg,
                                              const int* __restrict__ csr,
                                              const float* __restrict__ Bin,
                                              const float* __restrict__ dinv,
                                              const float* __restrict__ bias,
                                              const float* __restrict__ W2,
                                              float* __restrict__ Bout, int N) {
    __shared__ float lw[HID * HID];
    for (int i = threadIdx.x; i < HID * HID; i += 256) lw[i] = W2[i];
    __syncthreads();

    int lane = threadIdx.x & 7;
    int jb = lane * 4;
    int n  = blockIdx.x * 32 + (threadIdx.x >> 3);
    if (n >= N) return;

    const float2* B2 = (const float2*)Bin;
    hpack u0; u0.f2 = B2[(size_t)n * 8 + lane];     // self-loop term
    float2 l0 = __half22float2(u0.h2[0]);
    float2 l1 = __half22float2(u0.h2[1]);
    float4 acc = make_float4(l0.x, l0.y, l1.x, l1.y);

    int s = rowptr[n], cnt = deg[n];
    int k = 0;
    for (; k + 7 < cnt; k += 8) {
        int r0 = csr[s+k],   r1 = csr[s+k+1], r2 = csr[s+k+2], r3 = csr[s+k+3];
        int r4 = csr[s+k+4], r5 = csr[s+k+5], r6 = csr[s+k+6], r7 = csr[s+k+7];
        GLOAD(0, r0); GLOAD(1, r1); GLOAD(2, r2); GLOAD(3, r3);
        GLOAD(4, r4); GLOAD(5, r5); GLOAD(6, r6); GLOAD(7, r7);
        GACC(0); GACC(1); GACC(2); GACC(3); GACC(4); GACC(5); GACC(6); GACC(7);
    }
    for (; k + 3 < cnt; k += 4) {
        int r0 = csr[s+k], r1 = csr[s+k+1], r2 = csr[s+k+2], r3 = csr[s+k+3];
        GLOAD(0, r0); GLOAD(1, r1); GLOAD(2, r2); GLOAD(3, r3);
        GACC(0); GACC(1); GACC(2); GACC(3);
    }
    for (; k < cnt; ++k) {
        GLOAD(0, csr[s+k]); GACC(0);
    }
    float dv = dinv[n];
    float4 b4 = ((const float4*)bias)[lane];
    float4 o;
    o.x = fmaxf(fmaf(dv, acc.x, b4.x), 0.f);
    o.y = fmaxf(fmaf(dv, acc.y, b4.y), 0.f);
    o.z = fmaxf(fmaf(dv, acc.z, b4.z), 0.f);
    o.w = fmaxf(fmaf(dv, acc.w, b4.w), 0.f);

    // fused h1 @ W2 across the 8-lane group
    float t0 = 0.f, t1 = 0.f, t2 = 0.f, t3 = 0.f;
    #pragma unroll
    for (int sl = 0; sl < 8; ++sl) {
        float h0 = __shfl(o.x, sl, 8);
        float h1 = __shfl(o.y, sl, 8);
        float h2 = __shfl(o.z, sl, 8);
        float h3 = __shfl(o.w, sl, 8);
        const float* w0 = &lw[(sl * 4 + 0) * HID + jb];
        const float* w1 = &lw[(sl * 4 + 1) * HID + jb];
        const float* w2 = &lw[(sl * 4 + 2) * HID + jb];
        const float* w3 = &lw[(sl * 4 + 3) * HID + jb];
        t0 = fmaf(h0, w0[0], t0); t1 = fmaf(h0, w0[1], t1);
        t2 = fmaf(h0, w0[2], t2); t3 = fmaf(h0, w0[3], t3);
        t0 = fmaf(h1, w1[0], t0); t1 = fmaf(h1, w1[1], t1);
        t2 = fmaf(h1, w1[2], t2); t3 = fmaf(h1, w1[3], t3);
        t0 = fmaf(h2, w2[0], t0); t1 = fmaf(h2, w2[1], t1);
        t2 = fmaf(h2, w2[2], t2); t3 = fmaf(h2, w2[3], t3);
        t0 = fmaf(h3, w3[0], t0); t1 = fmaf(h3, w3[1], t1);
        t2 = fmaf(h3, w3[2], t2); t3 = fmaf(h3, w3[3], t3);
    }
    hpack w;
    w.h2[0] = __floats2half2_rn(t0 * dv, t1 * dv);
    w.h2[1] = __floats2half2_rn(t2 * dv, t3 * dv);
    ((float2*)Bout)[(size_t)n * 8 + lane] = w.f2;
}

// gather(B1) -> h2 = relu(...) -> s3 = dinv * (h2 . W3), f32 scalar out.
__global__ __launch_bounds__(256) void k_gxf3(const int* __restrict__ rowptr,
                                              const int* __restrict__ deg,
                                              const int* __restrict__ csr,
                                              const float* __restrict__ Bin,
                                              const float* __restrict__ dinv,
                                              const float* __restrict__ bias,
                                              const float* __restrict__ W3,
                                              float* __restrict__ s3, int N) {
    __shared__ float lw[HID];
    if (threadIdx.x < HID) lw[threadIdx.x] = W3[threadIdx.x];
    __syncthreads();

    int lane = threadIdx.x & 7;
    int jb = lane * 4;
    int n  = blockIdx.x * 32 + (threadIdx.x >> 3);
    if (n >= N) return;

    const float2* B2 = (const float2*)Bin;
    hpack u0; u0.f2 = B2[(size_t)n * 8 + lane];
    float2 l0 = __half22float2(u0.h2[0]);
    float2 l1 = __half22float2(u0.h2[1]);
    float4 acc = make_float4(l0.x, l0.y, l1.x, l1.y);

    int s = rowptr[n], cnt = deg[n];
    int k = 0;
    for (; k + 7 < cnt; k += 8) {
        int r0 = csr[s+k],   r1 = csr[s+k+1], r2 = csr[s+k+2], r3 = csr[s+k+3];
        int r4 = csr[s+k+4], r5 = csr[s+k+5], r6 = csr[s+k+6], r7 = csr[s+k+7];
        GLOAD(0, r0); GLOAD(1, r1); GLOAD(2, r2); GLOAD(3, r3);
        GLOAD(4, r4); GLOAD(5, r5); GLOAD(6, r6); GLOAD(7, r7);
        GACC(0); GACC(1); GACC(2); GACC(3); GACC(4); GACC(5); GACC(6); GACC(7);
    }
    for (; k + 3 < cnt; k += 4) {
        int r0 = csr[s+k], r1 = csr[s+k+1], r2 = csr[s+k+2], r3 = csr[s+k+3];
        GLOAD(0, r0); GLOAD(1, r1); GLOAD(2, r2); GLOAD(3, r3);
        GACC(0); GACC(1); GACC(2); GACC(3);
    }
    for (; k < cnt; ++k) {
        GLOAD(0, csr[s+k]); GACC(0);
    }
    float dv = dinv[n];
    float4 b4 = ((const float4*)bias)[lane];
    float4 o;
    o.x = fmaxf(fmaf(dv, acc.x, b4.x), 0.f);
    o.y = fmaxf(fmaf(dv, acc.y, b4.y), 0.f);
    o.z = fmaxf(fmaf(dv, acc.z, b4.z), 0.f);
    o.w = fmaxf(fmaf(dv, acc.w, b4.w), 0.f);

    float p = o.x * lw[jb] + o.y * lw[jb + 1] + o.z * lw[jb + 2] + o.w * lw[jb + 3];
    p += __shfl_xor(p, 1, 8);
    p += __shfl_xor(p, 2, 8);
    p += __shfl_xor(p, 4, 8);
    if (lane == 0) s3[n] = p * dv;
}

// out[n] = dinv[n] * (s3[n] + sum_nbrs s3[r]) + b3 ; 8 lanes/node strided.
__global__ __launch_bounds__(256) void k_gather1(const int* __restrict__ rowptr,
                                                 const int* __restrict__ deg,
                                                 const int* __restrict__ csr,
                                                 const float* __restrict__ s3,
                                                 const float* __restrict__ dinv,
                                                 const float* __restrict__ b3,
                                                 float* __restrict__ out, int N) {
    int lane = threadIdx.x & 7;
    int n    = blockIdx.x * 32 + (threadIdx.x >> 3);
    if (n >= N) return;

    int s = rowptr[n], cnt = deg[n];
    float acc = 0.f;
    for (int k = lane; k < cnt; k += 8) acc += s3[csr[s + k]];
    acc += __shfl_xor(acc, 1, 8);
    acc += __shfl_xor(acc, 2, 8);
    acc += __shfl_xor(acc, 4, 8);
    if (lane == 0) out[n] = fmaf(dinv[n], acc + s3[n], b3[0]);
}

// ======================= host launch =======================

static inline size_t align64(size_t x) { return (x + 63) & ~(size_t)63; }

extern "C" void kernel_launch(void* const* d_in, const int* in_sizes, int n_in,
                              void* d_out, int out_size, void* d_ws, size_t ws_size,
                              hipStream_t stream) {
    const float* x   = (const float*)d_in[0];
    const int*   ei  = (const int*)d_in[1];   // jax x64 disabled -> int32
    const float* W1  = (const float*)d_in[2];
    const float* b1  = (const float*)d_in[3];
    const float* W2  = (const float*)d_in[4];
    const float* b2  = (const float*)d_in[5];
    const float* W3  = (const float*)d_in[6];
    const float* b3  = (const float*)d_in[7];

    const int N = in_sizes[0] / IN_DIM;       // 100000
    const int E = in_sizes[1] / 2;            // 2400000
    const int* row = ei;                       // message source
    const int* col = ei + E;                   // aggregation target

    const int NB = (N + BSIZE - 1) / BSIZE;    // 196 buckets
    const size_t bktCap = (size_t)NB << CAPSH; // padded slot count

    // workspace layout (64B-aligned regions)
    char* p = (char*)d_ws;
    size_t off = 0;
    float* dinv   = (float*)(p + off); off = align64(off + (size_t)N * 4);
    float* B0     = (float*)(p + off); off = align64(off + (size_t)N * HID * 2);  // fp16 msgs
    float* B1     = (float*)(p + off); off = align64(off + (size_t)N * HID * 2);  // fp16 msgs
    float* s3     = (float*)(p + off); off = align64(off + (size_t)N * 4);
    int*   deg    = (int*)  (p + off); off = align64(off + (size_t)N * 4);
    int*   rowptr = (int*)  (p + off); off = align64(off + (size_t)N * 4);
    int*   cursor = (int*)  (p + off); off = align64(off + 256 * 4);
    int*   bpack  = (int*)  (p + off); off = align64(off + bktCap * 4);
    int*   csr    = (int*)  (p + off); off = align64(off + bktCap * 4);
    float* out    = (float*)d_out;

    const int gBuild = (E + CHUNK - 1) / CHUNK;   // 586
    const int gX64   = (N + 63) / 64;             // 1563 (xform part, 64 nodes/block)
    const int gNode  = (N + 31) / 32;             // 3125

    // ---- fused CSR bucket-sort + x@W1 (overlapped) ----
    k_init_cursor<<<1, 256, 0, stream>>>(cursor);
    k_fusedA<<<gBuild + gX64, 512, 0, stream>>>(row, col, cursor, bpack, x, W1, B0, E, N, gBuild);
    kC_fill <<<NB, 1024, 0, stream>>>(bpack, cursor, csr, rowptr, deg, dinv, B0, N);

    // ---- fused 3-layer GCN ----
    k_gxf2   <<<gNode, 256, 0, stream>>>(rowptr, deg, csr, B0, dinv, b1, W2, B1, N);
    k_gxf3   <<<gNode, 256, 0, stream>>>(rowptr, deg, csr, B1, dinv, b2, W3, s3, N);
    k_gather1<<<gNode, 256, 0, stream>>>(rowptr, deg, csr, s3, dinv, b3, out, N);
}